// Round 17
// baseline (3245.618 us; speedup 1.0000x reference)
//
#include <hip/hip_runtime.h>
#include <hip/hip_bf16.h>
#include <cstdint>

typedef float     f32x4  __attribute__((ext_vector_type(4)));
typedef __bf16    bf16x8 __attribute__((ext_vector_type(8)));
typedef unsigned short u16x4 __attribute__((ext_vector_type(4)));
typedef unsigned short u16x8 __attribute__((ext_vector_type(8)));
typedef unsigned short u16;

#define DI __device__ __forceinline__

DI float b2f(u16 u) { union { unsigned int i; float f; } x; x.i = ((unsigned int)u) << 16; return x.f; }
DI u16 f2b(float f) {
  union { float f; unsigned int i; } x; x.f = f;
  return (u16)((x.i + 0x7FFFu + ((x.i >> 16) & 1u)) >> 16);   // RNE
}

// direct global->LDS async copy, 16B per lane
DI void gload16(const void* g, void* l) {
  __builtin_amdgcn_global_load_lds(
      (const __attribute__((address_space(1))) unsigned int*)g,
      (__attribute__((address_space(3))) unsigned int*)l, 16, 0, 0);
}

#define VMCNT(n)  asm volatile("s_waitcnt vmcnt(" #n ")" ::: "memory")
#define LGKMCNT0() asm volatile("s_waitcnt lgkmcnt(0)" ::: "memory")
#define SBAR()    __builtin_amdgcn_s_barrier()
#define SCHED0()  __builtin_amdgcn_sched_barrier(0)

// 64B-row LDS swizzle: slot XOR (r ^ r>>2)&3
DI int swz64(int row) { return ((row ^ (row >> 2)) & 3) << 4; }

DI float gelu_f(float u) {
  const float y = 0.7978845608028654f * (u + 0.044715f * u * u * u);
  const float t = 1.0f - 2.0f / (__builtin_exp2f(y * 2.885390081777927f) + 1.0f);
  return 0.5f * u * (1.0f + t);
}

// ---------------------------------------------------------------------------
// Transpose + fp32->bf16 convert: src (R x C) f32 row-major -> dst (C x R) bf16
// ---------------------------------------------------------------------------
__global__ __launch_bounds__(256) void tpose_f32_bf16_kernel(
    const float* __restrict__ src, u16* __restrict__ dst, int R, int C)
{
  __shared__ float tile[32][33];
  const int c0 = blockIdx.x * 32, r0 = blockIdx.y * 32;
  const int tx = threadIdx.x, ty = threadIdx.y;
  #pragma unroll
  for (int i = 0; i < 4; ++i)
    tile[ty + i * 8][tx] = src[(long)(r0 + ty + i * 8) * C + c0 + tx];
  __syncthreads();
  #pragma unroll
  for (int i = 0; i < 4; ++i)
    dst[(long)(c0 + ty + i * 8) * R + r0 + tx] = f2b(tile[tx][ty + i * 8]);
}

// ---------------------------------------------------------------------------
// LayerNorm (row of 2048) fp32 -> bf16.
// ---------------------------------------------------------------------------
__global__ __launch_bounds__(256) void ln_bf16_kernel(
    const float* __restrict__ x, const float* __restrict__ gamma,
    const float* __restrict__ beta, u16* __restrict__ out)
{
  const long row = blockIdx.x;
  const float* xr = x + row * 2048;
  const int tid = threadIdx.x;
  float4 a = *(const float4*)(xr + tid * 8);
  float4 b = *(const float4*)(xr + tid * 8 + 4);
  float s  = a.x + a.y + a.z + a.w + b.x + b.y + b.z + b.w;
  float ss = a.x*a.x + a.y*a.y + a.z*a.z + a.w*a.w
           + b.x*b.x + b.y*b.y + b.z*b.z + b.w*b.w;
  #pragma unroll
  for (int off = 1; off < 64; off <<= 1) { s += __shfl_xor(s, off); ss += __shfl_xor(ss, off); }
  __shared__ float red[8];
  if ((tid & 63) == 0) { red[tid >> 6] = s; red[4 + (tid >> 6)] = ss; }
  __syncthreads();
  s  = red[0] + red[1] + red[2] + red[3];
  ss = red[4] + red[5] + red[6] + red[7];
  const float mu = s * (1.0f / 2048.0f);
  const float rs = rsqrtf(ss * (1.0f / 2048.0f) - mu * mu + 1e-5f);
  const float v[8] = {a.x, a.y, a.z, a.w, b.x, b.y, b.z, b.w};
  u16x8 o;
  #pragma unroll
  for (int j = 0; j < 8; ++j) {
    const int col = tid * 8 + j;
    o[j] = f2b((v[j] - mu) * rs * gamma[col] + beta[col]);
  }
  *(u16x8*)(out + row * 2048 + tid * 8) = o;
}

// ---------------------------------------------------------------------------
// ksum[d_row] = sum_s kT[d_row][s]
// ---------------------------------------------------------------------------
__global__ __launch_bounds__(256) void ksum_kernel(
    const u16* __restrict__ kT, float* __restrict__ ksum)
{
  const int gw = blockIdx.x * 4 + (threadIdx.x >> 6);
  const int lane = threadIdx.x & 63;
  const u16* r = kT + (long)gw * 2048;
  float s = 0.f;
  #pragma unroll
  for (int j = 0; j < 4; ++j) {
    u16x8 v = *(const u16x8*)(r + j * 512 + lane * 8);
    #pragma unroll
    for (int e = 0; e < 8; ++e) s += b2f(v[e]);
  }
  #pragma unroll
  for (int off = 1; off < 64; off <<= 1) s += __shfl_xor(s, off);
  if (lane == 0) ksum[gw] = s;
}

// ---------------------------------------------------------------------------
// den[b][h][s] = dot(q[b][s][h*128:], ksum[b][h][:])
// ---------------------------------------------------------------------------
__global__ __launch_bounds__(256) void den_kernel(
    const u16* __restrict__ q, const float* __restrict__ ksum, float* __restrict__ den)
{
  const long m = blockIdx.x;            // b*2048 + s
  const int tid = threadIdx.x;
  const int b = (int)(m >> 11);
  const int h = tid >> 4;
  const int dl = (tid & 15) * 8;
  const u16* qr = q + m * 2048 + h * 128 + dl;
  const float* ks = ksum + ((long)b * 16 + h) * 128 + dl;
  u16x8 v = *(const u16x8*)qr;
  float s = 0.f;
  #pragma unroll
  for (int e = 0; e < 8; ++e) s += b2f(v[e]) * ks[e];
  #pragma unroll
  for (int off = 1; off < 16; off <<= 1) s += __shfl_xor(s, off);
  if ((tid & 15) == 0) den[((long)b * 16 + h) * 2048 + (m & 2047)] = s;
}

// ---------------------------------------------------------------------------
// kv split-K reduce: out_bf16[i] = sum_{p<8} partial[p][i]
// ---------------------------------------------------------------------------
__global__ __launch_bounds__(256) void kvreduce_kernel(
    const float* __restrict__ p, u16* __restrict__ out)
{
  long i = ((long)blockIdx.x * 256 + threadIdx.x) * 4;
  float4 s = *(const float4*)(p + i);
  #pragma unroll
  for (int j = 1; j < 8; ++j) {
    float4 v = *(const float4*)(p + (long)j * 1048576 + i);
    s.x += v.x; s.y += v.y; s.z += v.z; s.w += v.w;
  }
  u16x4 o; o[0] = f2b(s.x); o[1] = f2b(s.y); o[2] = f2b(s.z); o[3] = f2b(s.w);
  *(u16x4*)(out + i) = o;
}

// ---------------------------------------------------------------------------
// RANK split-K reduce (f32 partials): out = sum_{p<NP} P[p] (+bias) (+old)
// ---------------------------------------------------------------------------
template<int NP, int OUTF32, int ACC>
__global__ __launch_bounds__(256) void rankreduce_kernel(
    const float* __restrict__ p, const float* __restrict__ bias, void* out)
{
  long i = ((long)blockIdx.x * 256 + threadIdx.x) * 4;
  float4 s = *(const float4*)(p + i);
  #pragma unroll
  for (int j = 1; j < NP; ++j) {
    float4 v = *(const float4*)(p + (long)j * 2097152 + i);
    s.x += v.x; s.y += v.y; s.z += v.z; s.w += v.w;
  }
  if (bias) {
    const int col = (int)(i & 255);
    s.x += bias[col]; s.y += bias[col + 1]; s.z += bias[col + 2]; s.w += bias[col + 3];
  }
  if (ACC) {
    float4 o = *(const float4*)((const float*)out + i);
    s.x += o.x; s.y += o.y; s.z += o.z; s.w += o.w;
  }
  if (OUTF32) {
    *(float4*)((float*)out + i) = s;
  } else {
    u16x4 o; o[0] = f2b(s.x); o[1] = f2b(s.y); o[2] = f2b(s.z); o[3] = f2b(s.w);
    *(u16x4*)((u16*)out + i) = o;
  }
}

// ---------------------------------------------------------------------------
// RANK reduce, 8 bf16 partials -> bf16 out (+bias)
// ---------------------------------------------------------------------------
__global__ __launch_bounds__(256) void rankreduce8b_kernel(
    const u16* __restrict__ p, const float* __restrict__ bias, u16* __restrict__ out)
{
  long i = ((long)blockIdx.x * 256 + threadIdx.x) * 4;
  float4 s = {0.f, 0.f, 0.f, 0.f};
  #pragma unroll
  for (int j = 0; j < 8; ++j) {
    u16x4 v = *(const u16x4*)(p + (long)j * 2097152 + i);
    s.x += b2f(v[0]); s.y += b2f(v[1]); s.z += b2f(v[2]); s.w += b2f(v[3]);
  }
  const int col = (int)(i & 255);
  s.x += bias[col]; s.y += bias[col + 1]; s.z += bias[col + 2]; s.w += bias[col + 3];
  u16x4 o; o[0] = f2b(s.x); o[1] = f2b(s.y); o[2] = f2b(s.z); o[3] = f2b(s.w);
  *(u16x4*)(out + i) = o;
}

// ---------------------------------------------------------------------------
// 256x128-tile bt-GEMM (ring-3 + swz64 + SWAPPED MFMA for vector epilogue):
// mfma(bf, af, acc) -> D(row=n, col=m): thread holds 4 consecutive N at fixed
// M -> float4/u16x4 stores + float4 resid loads along the contiguous N axis.
// grid (M/256, N/128). K % 32 == 0. 8 waves = 4M x 2N, acc[4][4] = 64 VGPR.
// ---------------------------------------------------------------------------
template<int OUTMODE, int RESID>
__global__ __launch_bounds__(512, 4) void btg128_kernel(
    const u16* __restrict__ A, const u16* __restrict__ Bt, void* Cv,
    const float* __restrict__ bias, const float* resid,
    int K, int lda, int ldb, int ldc)
{
  __shared__ char lds[73728];                // 3 regions x (A 16KB + B 8KB)
  const int tid = threadIdx.x;
  const int wave = tid >> 6, lane = tid & 63;
  const int lr = lane & 15, lk = lane >> 4;
  const int wr = wave >> 1, wc = wave & 1;   // 4M x 2N
  const char* Ab = (const char*)(A + (long)blockIdx.x * 256 * lda);
  const char* Bb = (const char*)(Bt + (long)blockIdx.y * 128 * ldb);
  const long ldaB = (long)lda * 2, ldbB = (long)ldb * 2;

  long srcA[2], srcB;
  int  dstA[2], dstB;
  #pragma unroll
  for (int j = 0; j < 2; ++j) {
    const int c = j * 512 + tid;            // A chunk 0..1023
    const int row = c >> 2;                 // 0..255 (64B rows)
    const int cb = (c & 3) * 16;
    srcA[j] = (long)row * ldaB + (cb ^ swz64(row));
    dstA[j] = c * 16;
  }
  {
    const int c = tid;                      // B chunk 0..511
    const int row = c >> 2;                 // 0..127
    const int cb = (c & 3) * 16;
    srcB = (long)row * ldbB + (cb ^ swz64(row));
    dstB = c * 16;
  }
  const int swzR = (lk * 16) ^ swz64(lr);

  f32x4 acc[4][4] = {};

  #define STGG(s, reg)                                                     \
    {                                                                      \
      char* R_ = lds + (reg) * 24576;                                      \
      const long colB_ = (long)(s) * 64;                                   \
      _Pragma("unroll")                                                    \
      for (int j = 0; j < 2; ++j)                                          \
        gload16(Ab + srcA[j] + colB_, R_ + dstA[j]);                       \
      gload16(Bb + srcB + colB_, R_ + 16384 + dstB);                       \
    }

  const int S = K >> 5;
  STGG(0, 0);
  if (S > 1) STGG(1, 1);
  if (S > 2) STGG(2, 2);
  int cur = 0;
  for (int s = 0; s < S; ++s) {
    if (s + 2 < S) { VMCNT(6); } else if (s + 1 < S) { VMCNT(3); } else { VMCNT(0); }
    SBAR(); SCHED0();
    {
      const char* R_ = lds + cur * 24576;
      bf16x8 af[4], bf[4];
      #pragma unroll
      for (int m = 0; m < 4; ++m)
        af[m] = *(const bf16x8*)(R_ + (wr * 64 + m * 16 + lr) * 64 + swzR);
      #pragma unroll
      for (int n = 0; n < 4; ++n)
        bf[n] = *(const bf16x8*)(R_ + 16384 + (wc * 64 + n * 16 + lr) * 64 + swzR);
      __builtin_amdgcn_s_setprio(1);
      #pragma unroll
      for (int m = 0; m < 4; ++m)
        #pragma unroll
        for (int n = 0; n < 4; ++n)
          acc[m][n] = __builtin_amdgcn_mfma_f32_16x16x32_bf16(bf[n], af[m], acc[m][n], 0, 0, 0);
      __builtin_amdgcn_s_setprio(0);
    }
    SBAR(); SCHED0();                        // all waves done reading region cur
    if (s + 3 < S) STGG(s + 3, cur);         // (s+3)%3 == s%3 == cur
    cur = (cur == 2) ? 0 : cur + 1;
  }
  #undef STGG

  // epilogue (swapped layout): thread holds rows=n (4 consec), col=m
  #pragma unroll
  for (int m = 0; m < 4; ++m) {
    #pragma unroll
    for (int n = 0; n < 4; ++n) {
      const int gm  = blockIdx.x * 256 + wr * 64 + m * 16 + lr;
      const int gn0 = blockIdx.y * 128 + wc * 64 + n * 16 + lk * 4;
      float4 bi = {0.f, 0.f, 0.f, 0.f};
      if (bias) bi = *(const float4*)(bias + gn0);
      float4 v4;
      v4.x = acc[m][n][0] + bi.x; v4.y = acc[m][n][1] + bi.y;
      v4.z = acc[m][n][2] + bi.z; v4.w = acc[m][n][3] + bi.w;
      if (RESID) {
        float4 r = *(const float4*)(resid + (long)gm * ldc + gn0);
        v4.x += r.x; v4.y += r.y; v4.z += r.z; v4.w += r.w;
      }
      if (OUTMODE == 0) {
        u16x4 pk; pk[0] = f2b(v4.x); pk[1] = f2b(v4.y); pk[2] = f2b(v4.z); pk[3] = f2b(v4.w);
        *(u16x4*)((u16*)Cv + (long)gm * ldc + gn0) = pk;
      } else {
        *(float4*)((float*)Cv + (long)gm * ldc + gn0) = v4;
      }
    }
  }
}

// ---------------------------------------------------------------------------
// Fused q/k/v GEMM (ring-3 + swz64; z==0 uses swapped MFMA for vector stores)
// grid (32,16,3).
// ---------------------------------------------------------------------------
__global__ __launch_bounds__(512, 4) void qkv256_kernel(
    const u16* __restrict__ A, const u16* __restrict__ Wt0,
    u16* __restrict__ Qout, u16* __restrict__ Kout, u16* __restrict__ Vout,
    const float* __restrict__ bq, const float* __restrict__ bk,
    const float* __restrict__ bv)
{
  __shared__ char lds[73728];                // 3 regions x (A 16KB + B 8KB)
  const int tid = threadIdx.x;
  const int wave = tid >> 6, lane = tid & 63;
  const int lr = lane & 15, lk = lane >> 4;
  const int wr = wave >> 1, wc = wave & 1;   // 4M x 2N
  const int z = blockIdx.z;
  const char* Ab = (const char*)(A + (long)blockIdx.x * 256 * 2048);
  const char* Bb = (const char*)(Wt0 + (long)z * 4194304 + (long)blockIdx.y * 128 * 2048);

  long srcA[2], srcB;
  int  dstA[2], dstB;
  #pragma unroll
  for (int j = 0; j < 2; ++j) {
    const int c = j * 512 + tid;            // A chunk 0..1023
    const int row = c >> 2;                 // 0..255 (64B rows)
    const int cb = (c & 3) * 16;
    srcA[j] = (long)row * 4096 + (cb ^ swz64(row));
    dstA[j] = c * 16;
  }
  {
    const int c = tid;                      // B chunk 0..511
    const int row = c >> 2;                 // 0..127
    const int cb = (c & 3) * 16;
    srcB = (long)row * 4096 + (cb ^ swz64(row));
    dstB = c * 16;
  }
  const int swzR = (lk * 16) ^ swz64(lr);

  f32x4 acc[4][4] = {};

  #define STGQ(s, reg)                                                     \
    {                                                                      \
      char* R_ = lds + (reg) * 24576;                                      \
      const long colB_ = (long)(s) * 64;                                   \
      _Pragma("unroll")                                                    \
      for (int j = 0; j < 2; ++j)                                          \
        gload16(Ab + srcA[j] + colB_, R_ + dstA[j]);                       \
      gload16(Bb + srcB + colB_, R_ + 16384 + dstB);                       \
    }

  const int S = 64;                          // K=2048 / 32
  STGQ(0, 0); STGQ(1, 1); STGQ(2, 2);        // 9 loads/thread outstanding
  int cur = 0;
  const bool swapq = (z == 0);
  for (int s = 0; s < S; ++s) {
    if (s + 2 < S) { VMCNT(6); } else if (s + 1 < S) { VMCNT(3); } else { VMCNT(0); }
    SBAR(); SCHED0();
    {
      const char* R_ = lds + cur * 24576;
      bf16x8 af[4], bf[4];
      #pragma unroll
      for (int m = 0; m < 4; ++m)
        af[m] = *(const bf16x8*)(R_ + (wr * 64 + m * 16 + lr) * 64 + swzR);
      #pragma unroll
      for (int n = 0; n < 4; ++n)
        bf[n] = *(const bf16x8*)(R_ + 16384 + (wc * 64 + n * 16 + lr) * 64 + swzR);
      __builtin_amdgcn_s_setprio(1);
      if (swapq) {
        #pragma unroll
        for (int m = 0; m < 4; ++m)
          #pragma unroll
          for (int n = 0; n < 4; ++n)
            acc[m][n] = __builtin_amdgcn_mfma_f32_16x16x32_bf16(bf[n], af[m], acc[m][n], 0, 0, 0);
      } else {
        #pragma unroll
        for (int m = 0; m < 4; ++m)
          #pragma unroll
          for (int n = 0; n < 4; ++n)
            acc[m][n] = __builtin_amdgcn_mfma_f32_16x16x32_bf16(af[m], bf[n], acc[m][n], 0, 0, 0);
      }
      __builtin_amdgcn_s_setprio(0);
    }
    SBAR(); SCHED0();
    if (s + 3 < S) STGQ(s + 3, cur);
    cur = (cur == 2) ? 0 : cur + 1;
  }
  #undef STGQ

  if (z == 0) {
    // swapped layout: rows = n (4 consec at lk*4), col = m (lr) -> u16x4 along N
    #pragma unroll
    for (int m = 0; m < 4; ++m) {
      #pragma unroll
      for (int n = 0; n < 4; ++n) {
        const int gm  = blockIdx.x * 256 + wr * 64 + m * 16 + lr;
        const int gn0 = blockIdx.y * 128 + wc * 64 + n * 16 + lk * 4;
        float4 bi = *(const float4*)(bq + gn0);
        u16x4 pk;
        #pragma unroll
        for (int i = 0; i < 4; ++i) {
          float val = acc[m][n][i] + ((const float*)&bi)[i];
          val = (val > 0.f) ? (val + 1.f) : __builtin_exp2f(val * 1.4426950408889634f);
          pk[i] = f2b(val);
        }
        *(u16x4*)(Qout + (long)gm * 2048 + gn0) = pk;
      }
    }
  } else {
    const float* bias = (z == 1) ? bk : bv;
    #pragma unroll
    for (int m = 0; m < 4; ++m) {
      #pragma unroll
      for (int n = 0; n < 4; ++n) {
        const int gm0 = blockIdx.x * 256 + wr * 64 + m * 16 + lk * 4;
        const int gn  = blockIdx.y * 128 + wc * 64 + n * 16 + lr;
        float v4[4];
        #pragma unroll
        for (int i = 0; i < 4; ++i) {
          float val = acc[m][n][i] + bias[gn];
          if (z == 1)  // k: elu(x)+1
            val = (val > 0.f) ? (val + 1.f) : __builtin_exp2f(val * 1.4426950408889634f);
          v4[i] = val;
        }
        u16* C = (z == 1) ? Kout : Vout;     // transposed (B,H,HD,S)
        const int b = gm0 >> 11, s = gm0 & 2047;
        const int h = gn >> 7,  d = gn & 127;
        u16x4 p;
        p[0] = f2b(v4[0]); p[1] = f2b(v4[1]); p[2] = f2b(v4[2]); p[3] = f2b(v4[3]);
        *(u16x4*)(C + (long)((b * 16 + h) * 128 + d) * 2048 + s) = p;
      }
    }
  }
}

// ---------------------------------------------------------------------------
// 128x128-tile z-batched bt-GEMM: ring + reg-dbuf + swz64 (tail kernels).
// Requires K % 64 == 0, K >= 128.
// ---------------------------------------------------------------------------
template<int ACT, int OUTMODE, int RESID, int ACCUM, int DIVDEN>
__global__ __launch_bounds__(256) void btgemm_kernel(
    const u16* __restrict__ A, const u16* __restrict__ Bt, void* Cv,
    const float* __restrict__ bias, const float* resid, const float* __restrict__ den,
    int M, int N, int K, int lda, int ldb, int ldc, int ZMOD,
    long sAh, long sAl, long sBh, long sBl, long sCh, long sCl, long sDh, long sDl)
{
  __shared__ char lds[65536];
  const int tid = threadIdx.x;
  const int wave = tid >> 6, lane = tid & 63;
  const int lr = lane & 15, lk = lane >> 4;
  const int wr = wave >> 1, wc = wave & 1;
  const int z = blockIdx.z;
  const int zh = z / ZMOD, zl = z % ZMOD;
  const char* Ab = (const char*)(A + zh * sAh + zl * sAl + (long)blockIdx.x * 128 * lda);
  const char* Bb = (const char*)(Bt + zh * sBh + zl * sBl + (long)blockIdx.y * 128 * ldb);
  const long ldaB = (long)lda * 2, ldbB = (long)ldb * 2;

  long srcA[2], srcB[2];
  int  dstO[2];
  #pragma unroll
  for (int j = 0; j < 2; ++j) {
    const int c = j * 256 + tid;            // chunk 0..511
    const int row = c >> 2;                 // 0..127 (64B rows)
    const int cb = (c & 3) * 16;
    srcA[j] = (long)row * ldaB + (cb ^ swz64(row));
    srcB[j] = (long)row * ldbB + (cb ^ swz64(row));
    dstO[j] = c * 16;
  }
  const int swzR = (lk * 16) ^ swz64(lr);

  f32x4 acc[4][4] = {};
  bf16x8 a_af[4], a_bf[4], b_af[4], b_bf[4];

  #define STG7(s)                                                          \
    { char* R_ = lds + ((s) & 3) * 16384; const long cB_ = (long)(s) * 64; \
      _Pragma("unroll") for (int j = 0; j < 2; ++j) {                      \
        gload16(Ab + srcA[j] + cB_, R_ + dstO[j]);                         \
        gload16(Bb + srcB[j] + cB_, R_ + 8192 + dstO[j]); } }

  #define RD7(P, s)                                                       \
    { const char* R_ = lds + ((s) & 3) * 16384;                            \
      _Pragma("unroll") for (int m = 0; m < 4; ++m)                        \
        P##af[m] = *(const bf16x8*)(R_ + (wr * 64 + m * 16 + lr) * 64 + swzR); \
      _Pragma("unroll") for (int n = 0; n < 4; ++n)                        \
        P##bf[n] = *(const bf16x8*)(R_ + 8192 + (wc * 64 + n * 16 + lr) * 64 + swzR); }

  #define MM7(P)                                                           \
    { __builtin_amdgcn_s_setprio(1);                                       \
      _Pragma("unroll") for (int m = 0; m < 4; ++m)                        \
        _Pragma("unroll") for (int n = 0; n < 4; ++n)                      \
          acc[m][n] = __builtin_amdgcn_mfma_f32_16x16x32_bf16(P##af[m], P##bf[n], acc[m][n], 0, 0, 0); \
      __builtin_amdgcn_s_setprio(0); }

  const int S = K >> 5;                     // even, >= 4
  STG7(0); STG7(1); STG7(2);
  VMCNT(8); SBAR(); SCHED0();
  RD7(a_, 0);
  for (int s = 0; s < S - 2; s += 2) {
    VMCNT(4); SBAR(); SCHED0();
    RD7(b_, s + 1);
    if (s + 3 < S) STG7(s + 3);
    SCHED0();
    MM7(a_);
    VMCNT(4); SBAR(); SCHED0();
    RD7(a_, s + 2);
    if (s + 4 < S) STG7(s + 4);
    SCHED0();
    MM7(b_);
  }
  VMCNT(0); SBAR(); SCHED0();
  RD7(b_, S - 1);
  SCHED0();
  MM7(a_);
  MM7(b_);
  #undef STG7
  #undef RD7
  #undef MM7

  const long cbase = (long)zh * sCh + (long)zl * sCl;
  #pragma unroll
  for (int m = 0; m < 4; ++m) {
    #pragma unroll
    for (int n = 0; n < 4; ++n) {
      const int gm0 = blockIdx.x * 128 + wr * 64 + m * 16 + lk * 4;
      const int gn  = blockIdx.y * 128 + wc * 64 + n * 16 + lr;
      float v4[4];
      #pragma unroll
      for (int i = 0; i < 4; ++i) {
        float val = acc[m][n][i];
        if (bias) val += bias[gn];
        if (ACT == 1) val = (val > 0.f) ? (val + 1.f) : __builtin_exp2f(val * 1.4426950408889634f);
        if (ACT == 2) val = gelu_f(val);
        if (DIVDEN) val = val / (den[(long)zh * sDh + (long)zl * sDl + gm0 + i] + 1e-6f);
        if (RESID) val += resid[cbase + (long)(gm0 + i) * ldc + gn];
        if (ACCUM) val += ((const float*)Cv)[cbase + (long)(gm0 + i) * ldc + gn];
        v4[i] = val;
      }
      if (OUTMODE == 0) {
        u16* C = (u16*)Cv;
        #pragma unroll
        for (int i = 0; i < 4; ++i) C[cbase + (long)(gm0 + i) * ldc + gn] = f2b(v4[i]);
      } else if (OUTMODE == 1) {
        float* C = (float*)Cv;
        #pragma unroll
        for (int i = 0; i < 4; ++i) C[cbase + (long)(gm0 + i) * ldc + gn] = v4[i];
      } else {
        u16* C = (u16*)Cv;
        const int b = gm0 >> 11, s = gm0 & 2047;
        const int h = gn >> 7,  d = gn & 127;
        u16x4 p;
        p[0] = f2b(v4[0]); p[1] = f2b(v4[1]); p[2] = f2b(v4[2]); p[3] = f2b(v4[3]);
        *(u16x4*)(C + (long)((b * 16 + h) * 128 + d) * 2048 + s) = p;
      }
    }
  }
}

// ---------------------------------------------------------------------------
// Fused FFN middle v5: 64-row M-tile, hg split 8 (grid 128x8), bf16 partials.
// 512 thr, LDS 72KB, 2 blocks/CU. (unchanged)
// ---------------------------------------------------------------------------
__global__ __launch_bounds__(512, 4) void ffnmid_kernel(
    const u16* __restrict__ T1,   // [8192][256] bf16
    const u16* __restrict__ W2T,  // [8192][256] bf16 (rows = HID)
    const u16* __restrict__ W3T,  // [256][8192] bf16 (rows = rank)
    const float* __restrict__ b2, // [8192]
    u16* __restrict__ RP)         // [8][8192][256] bf16 partials
{
  __shared__ char Wb[2][32768];   // W2s [32][512B] swz(r&7)<<4 ; W3s [256][64B] swz(r&3)<<4
  __shared__ char Ps[8192];       // [64][128B] swz(m&7)<<4, cols 0..63B used
  const int tid = threadIdx.x;
  const int wave = tid >> 6, lane = tid & 63;
  const int lr = lane & 15, lk = lane >> 4;
  const int wn  = wave & 1;       // stage-1 A(W2) n-frag (n0 = wn*16)
  const int wm  = wave >> 1;      // stage-1 B(T1) m-frag (m0 = wm*16)
  const int wmm = wave & 1;       // stage-2 m-group (m0 = wmm*32)
  const int wrr = wave >> 1;      // stage-2 r-group (r0 = wrr*64)
  const int mb = blockIdx.x, hg = blockIdx.y;

  // T1 fragment -> registers (B-operand layout: row=lr, k=lk*8+e), once.
  bf16x8 t1r[8];
  {
    const long row = (long)mb * 64 + wm * 16 + lr;
    #pragma unroll
    for (int kx = 0; kx < 8; ++kx)
      t1r[kx] = *(const bf16x8*)(T1 + row * 256 + kx * 32 + lk * 8);
  }

  #define STG_SLICE(it, buf)                                               \
    {                                                                      \
      const long h0_ = (long)hg * 1024 + (long)(it) * 32;                  \
      const char* s2_ = (const char*)W2T + h0_ * 512;                      \
      _Pragma("unroll")                                                    \
      for (int j = 0; j < 2; ++j) {                                        \
        const int c = j * 512 + tid;             /* 0..1023 */             \
        const int r = c >> 5;                    /* 0..31  */              \
        const int cb = (c & 31) * 16;                                      \
        gload16(s2_ + r * 512 + (cb ^ ((r & 7) << 4)), Wb[buf] + c * 16);  \
      }                                                                    \
      _Pragma("unroll")                                                    \
      for (int j = 0; j < 2; ++j) {                                        \
        const int c = j * 512 + tid;             /* 0..1023 */             \
        const int r = c >> 2;                    /* 0..255 */              \
        const int cb = (c & 3) * 16;                                       \
        gload16((const char*)W3T + (long)r * 16384 + h0_ * 2 +             \
                    (cb ^ ((r & 3) << 4)),                                 \
                Wb[buf] + 16384 + c * 16);                                 \
      }                                                                    \
    }

  const float* bbase = b2 + (long)hg * 1024 + wn * 16 + lk * 4;
  float4 bias = *(const float4*)bbase;
  STG_SLICE(0, 0);
  VMCNT(0); SBAR();

  f32x4 acc2[2][4] = {};

  for (int it = 0; it < 32; ++it) {
    const int cur = it & 1;
    const char* W2s = Wb[cur];
    const char* W3s = Wb[cur] + 16384;

    float4 bias_n = bias;
    if (it + 1 < 32) {
      STG_SLICE(it + 1, cur ^ 1);
      bias_n = *(const float4*)(bbase + (it + 1) * 32);
    }
    SCHED0();

    // stage-1: D(n,m) = W2slice @ T1^T   (32 x 64, K=256), T1 in regs
    f32x4 p = {};
    #pragma unroll
    for (int kx = 0; kx < 8; ++kx) {
      const int nn = wn * 16 + lr;           // A row
      bf16x8 w2f = *(const bf16x8*)(W2s + nn * 512 + (((kx * 32 + lk * 8) * 2) ^ ((nn & 7) << 4)));
      p = __builtin_amdgcn_mfma_f32_16x16x32_bf16(w2f, t1r[kx], p, 0, 0, 0);
    }
    // gelu + vector write: thread holds (n = wn*16+lk*4+i, m = wm*16+lr)
    {
      const int m = wm * 16 + lr;
      u16x4 pk;
      pk[0] = f2b(gelu_f(p[0] + bias.x));
      pk[1] = f2b(gelu_f(p[1] + bias.y));
      pk[2] = f2b(gelu_f(p[2] + bias.z));
      pk[3] = f2b(gelu_f(p[3] + bias.w));
      *(u16x4*)(Ps + m * 128 + ((wn * 32 + lk * 8) ^ ((m & 7) << 4))) = pk;
    }
    LGKMCNT0();   // cross-wave ds_write -> ds_read: drain before barrier
    SBAR();

    // stage-2: acc2 += P @ W3slice^T   (64 x 256, K=32), 2m x 4r frags
    {
      bf16x8 af[2], bf[4];
      #pragma unroll
      for (int fm = 0; fm < 2; ++fm) {
        const int m = wmm * 32 + fm * 16 + lr;
        af[fm] = *(const bf16x8*)(Ps + m * 128 + ((lk * 16) ^ ((m & 7) << 4)));
      }
      #pragma unroll
      for (int fr = 0; fr < 4; ++fr) {
        const int r = wrr * 64 + fr * 16 + lr;
        bf[fr] = *(const bf16x8*)(W3s + r * 64 + ((lk * 16) ^ ((r & 3) << 4)));
      }
      __builtin_amdgcn_s_setprio(1);
      #pragma unroll
      for (int fm = 0; fm < 2; ++fm)
        #pragma unroll
        for (int fr = 0; fr < 4; ++fr)
          acc2[fm][fr] = __builtin_amdgcn_mfma_f32_16x16x32_bf16(af[fm], bf[fr], acc2[fm][fr], 0, 0, 0);
      __builtin_amdgcn_s_setprio(0);
    }
    bias = bias_n;
    VMCNT(0);   // next slice + bias landed (overlapped with compute above)
    SBAR();     // Ps/W3s reads consumed -> safe to overwrite next iter
  }
  #undef STG_SLICE

  // epilogue: partial bf16 [64][256]
  u16* out = RP + (long)hg * 2097152 + (long)mb * 64 * 256;
  #pragma unroll
  for (int fm = 0; fm < 2; ++fm) {
    #pragma unroll
    for (int fr = 0; fr < 4; ++fr) {
      const int r = wrr * 64 + fr * 16 + lr;
      #pragma unroll
      for (int i = 0; i < 4; ++i) {
        const int m = wmm * 32 + fm * 16 + lk * 4 + i;
        out[(long)m * 256 + r] = f2b(acc2[fm][fr][i]);
      }
    }
  }
}

// ---------------------------------------------------------------------------
extern "C" void kernel_launch(void* const* d_in, const int* in_sizes, int n_in,
                              void* d_out, int out_size, void* d_ws, size_t ws_size,
                              hipStream_t stream) {
  const float* x   = (const float*)d_in[0];
  const float* Wq  = (const float*)d_in[1];
  const float* bq  = (const float*)d_in[2];
  const float* Wk  = (const float*)d_in[3];
  const float* bk  = (const float*)d_in[4];
  const float* Wv  = (const float*)d_in[5];
  const float* bv  = (const float*)d_in[6];
  const float* Wo  = (const float*)d_in[7];
  const float* bo  = (const float*)d_in[8];
  const float* g1  = (const float*)d_in[9];
  const float* be1 = (const float*)d_in[10];
  const float* g2  = (const float*)d_in[11];
  const float* be2 = (const float*)d_in[12];
  const float* W1  = (const float*)d_in[13];
  const float* b1  = (const float*)d_in[14];
  const float* W2  = (const float*)d_in[15];
  const float* b2  = (const float*)d_in[16];
  const float* W3  = (const float*)d_in[17];
  const float* b3  = (const float*)d_in[18];
  const float* W4  = (const float*)d_in[19];
  const float* b4  = (const float*)d_in[20];
  float* xout = (float*)d_out;
  char* ws = (char*)d_ws;

  // workspace layout (bytes); total ~172.6 MB
  constexpr long DD2 = 2048L * 2048 * 2;          // 8 MB
  constexpr size_t oWqT = 0;
  constexpr size_t oWkT = oWqT + DD2;
  constexpr size_t oWvT = oWkT + DD2;
  constexpr size_t oWoT = oWvT + DD2;
  constexpr size_t oW1T = oWoT + DD2;             // 256x2048 bf16 (1 MB)
  constexpr size_t oW2T = oW1T + 256L * 2048 * 2; // 8192x256 bf16 (4 MB)
  constexpr size_t oW3T = oW2T + 8192L * 256 * 2; // 256x8192 bf16 (4 MB)
  constexpr size_t oW4T = oW3T + 256L * 8192 * 2; // 2048x256 bf16 (1 MB)
  constexpr size_t oH1  = oW4T + 2048L * 256 * 2; // 32MB: h1 / kvpart / attnN / t1-partials
  constexpr size_t oQ   = oH1 + 8192L * 2048 * 2; // 32MB: q / h2 / t3b
  constexpr size_t oKT  = oQ  + 8192L * 2048 * 2; // 32MB: kT / t1
  constexpr size_t oVT  = oKT + 8192L * 2048 * 2; // 32MB: vT / ffn partials (bf16 x8)
  constexpr size_t oKVT = oVT + 8192L * 2048 * 2; // 64x128x128 bf16 (2MB)
  constexpr size_t oKS  = oKVT + 64L * 128 * 128 * 2;
  constexpr size_t oDEN = oKS + 64L * 128 * 4;

  u16* WqT = (u16*)(ws + oWqT);
  u16* WkT = (u16*)(ws + oWkT);
  u16* WvT = (u16*)(ws + oWvT);
  u16* WoT = (u16*)(ws + oWoT);
  u16* W1T = (u16*)(ws + oW1T);
  u16* W2T = (u16*)(ws + oW2T);
  u16* W3T = (u16*)(ws + oW3T);
  u16* W4T = (u16*)(ws + oW4T);
  u16* H1    = (u16*)(ws + oH1);    // h1; kv partials; attnN; t1 split-K partials
  float* KVP = (float*)(ws + oH1);
  float* RP1 = (float*)(ws + oH1);  // t1 partials [4][8192][256] f32
  u16* Qb    = (u16*)(ws + oQ);     // q; h2
  u16* T3B   = (u16*)(ws + oQ + 8L * 1024 * 1024); // t3 bf16 (4MB; h2 dead)
  u16* KT    = (u16*)(ws + oKT);    // kT; then t1
  u16* T1    = (u16*)(ws + oKT);
  u16* VT    = (u16*)(ws + oVT);    // vT; then ffn partials
  u16* RPF   = (u16*)(ws + oVT);    // ffn partials [8][8192][256] bf16 (32MB)
  u16* KVT = (u16*)(ws + oKVT);
  float* KS  = (float*)(ws + oKS);
  float* DEN = (float*)(ws + oDEN);
  u16* H2  = Qb;

  const dim3 tb32(32, 8);
  tpose_f32_bf16_kernel<<<dim3(64, 64), tb32, 0, stream>>>(Wq, WqT, 2048, 2048);
  tpose_f32_bf16_kernel<<<dim3(64, 64), tb32, 0, stream>>>(Wk, WkT, 2048, 2048);
  tpose_f32_bf16_kernel<<<dim3(64, 64), tb32, 0, stream>>>(Wv, WvT, 2048, 2048);
  tpose_f32_bf16_kernel<<<dim3(64, 64), tb32, 0, stream>>>(Wo, WoT, 2048, 2048);
  tpose_f32_bf16_kernel<<<dim3(8, 64),  tb32, 0, stream>>>(W1, W1T, 2048, 256);
  tpose_f32_bf16_kernel<<<dim3(256, 8), tb32, 0, stream>>>(W2, W2T, 256, 8192);
  tpose_f32_bf16_kernel<<<dim3(8, 256), tb32, 0, stream>>>(W3, W3T, 8192, 256);
  tpose_f32_bf16_kernel<<<dim3(64, 8),  tb32, 0, stream>>>(W4, W4T, 256, 2048);

  // h1 = LN1(x)
  ln_bf16_kernel<<<8192, 256, 0, stream>>>(x, g1, be1, H1);

  // fused q,k,v projections: ring-3 + swz64 + vector-Q-epilogue
  qkv256_kernel<<<dim3(32, 16, 3), 512, 0, stream>>>(
      H1, WqT, Qb, KT, VT, bq, bk, bv);

  // ksum over S, den = q.ksum
  ksum_kernel<<<2048, 256, 0, stream>>>(KT, KS);
  den_kernel<<<8192, 256, 0, stream>>>(Qb, KS, DEN);

  // kv split-K (z = head*8 + K-chunk of 256) -> f32 partials -> reduce
  btgemm_kernel<0, 1, 0, 0, 0><<<dim3(1, 1, 512), 256, 0, stream>>>(
      VT, KT, KVP, nullptr, nullptr, nullptr, 128, 128, 256, 2048, 2048, 128, 8,
      262144, 256, 262144, 256, 16384, 1048576, 0, 0);
  kvreduce_kernel<<<1024, 256, 0, stream>>>(KVP, KVT);

  // num = q @ kvT ; /(den+eps) -> attnN (bf16, (B,S,D), into H1 region)
  btgemm_kernel<0, 0, 0, 0, 1><<<dim3(16, 1, 64), 256, 0, stream>>>(
      Qb, KVT, H1, nullptr, nullptr, DEN, 2048, 128, 128, 2048, 128, 2048, 16,
      4194304, 128, 262144, 16384, 4194304, 128, 32768, 2048);

  // x2 = x + attnN@Wo + bo -> d_out (f32)  [swapped-epilogue btg128]
  btg128_kernel<1, 1><<<dim3(32, 16), 512, 0, stream>>>(
      H1, WoT, xout, bo, x, 2048, 2048, 2048, 2048);

  // h2 = LN2(x2)
  ln_bf16_kernel<<<8192, 256, 0, stream>>>(xout, g2, be2, H2);

  // t1 = h2@W1 + b1 : split-K x4 (K-sub 512) -> reduce bf16
  btgemm_kernel<0, 1, 0, 0, 0><<<dim3(64, 2, 4), 256, 0, stream>>>(
      H2, W1T, RP1, nullptr, nullptr, nullptr, 8192, 256, 512, 2048, 2048, 256, 4,
      0, 512, 0, 512, 0, 2097152, 0, 0);
  rankreduce_kernel<4, 0, 0><<<2048, 256, 0, stream>>>(RP1, b1, T1);

  // fused FFN middle: t3 partials = gelu(t1@W2+b2)@W3, t2 never to HBM
  ffnmid_kernel<<<dim3(128, 8), 512, 0, stream>>>(T1, W2T, W3T, b2, RPF);
  rankreduce8b_kernel<<<2048, 256, 0, stream>>>(RPF, b3, T3B);

  // out = x2 + t3@W4 + b4 (resid = d_out)  [swapped-epilogue btg128, K=256]
  btg128_kernel<1, 1><<<dim3(32, 16), 512, 0, stream>>>(
      T3B, W4T, xout, b4, xout, 256, 256, 256, 2048);
}

// Round 18
// 678.157 us; speedup vs baseline: 4.7859x; 4.7859x over previous
//
#include <hip/hip_runtime.h>
#include <hip/hip_bf16.h>
#include <cstdint>

typedef float     f32x4  __attribute__((ext_vector_type(4)));
typedef __bf16    bf16x8 __attribute__((ext_vector_type(8)));
typedef unsigned short u16x4 __attribute__((ext_vector_type(4)));
typedef unsigned short u16x8 __attribute__((ext_vector_type(8)));
typedef unsigned short u16;

#define DI __device__ __forceinline__

DI float b2f(u16 u) { union { unsigned int i; float f; } x; x.i = ((unsigned int)u) << 16; return x.f; }
DI u16 f2b(float f) {
  union { float f; unsigned int i; } x; x.f = f;
  return (u16)((x.i + 0x7FFFu + ((x.i >> 16) & 1u)) >> 16);   // RNE
}

// direct global->LDS async copy, 16B per lane
DI void gload16(const void* g, void* l) {
  __builtin_amdgcn_global_load_lds(
      (const __attribute__((address_space(1))) unsigned int*)g,
      (__attribute__((address_space(3))) unsigned int*)l, 16, 0, 0);
}

#define VMCNT(n)  asm volatile("s_waitcnt vmcnt(" #n ")" ::: "memory")
#define LGKMCNT0() asm volatile("s_waitcnt lgkmcnt(0)" ::: "memory")
#define SBAR()    __builtin_amdgcn_s_barrier()
#define SCHED0()  __builtin_amdgcn_sched_barrier(0)

// 64B-row LDS swizzle: slot XOR (r ^ r>>2)&3
DI int swz64(int row) { return ((row ^ (row >> 2)) & 3) << 4; }

DI float gelu_f(float u) {
  const float y = 0.7978845608028654f * (u + 0.044715f * u * u * u);
  const float t = 1.0f - 2.0f / (__builtin_exp2f(y * 2.885390081777927f) + 1.0f);
  return 0.5f * u * (1.0f + t);
}

// ---------------------------------------------------------------------------
// Transpose + fp32->bf16 convert: src (R x C) f32 row-major -> dst (C x R) bf16
// ---------------------------------------------------------------------------
__global__ __launch_bounds__(256) void tpose_f32_bf16_kernel(
    const float* __restrict__ src, u16* __restrict__ dst, int R, int C)
{
  __shared__ float tile[32][33];
  const int c0 = blockIdx.x * 32, r0 = blockIdx.y * 32;
  const int tx = threadIdx.x, ty = threadIdx.y;
  #pragma unroll
  for (int i = 0; i < 4; ++i)
    tile[ty + i * 8][tx] = src[(long)(r0 + ty + i * 8) * C + c0 + tx];
  __syncthreads();
  #pragma unroll
  for (int i = 0; i < 4; ++i)
    dst[(long)(c0 + ty + i * 8) * R + r0 + tx] = f2b(tile[tx][ty + i * 8]);
}

// ---------------------------------------------------------------------------
// LayerNorm (row of 2048) fp32 -> bf16.
// ---------------------------------------------------------------------------
__global__ __launch_bounds__(256) void ln_bf16_kernel(
    const float* __restrict__ x, const float* __restrict__ gamma,
    const float* __restrict__ beta, u16* __restrict__ out)
{
  const long row = blockIdx.x;
  const float* xr = x + row * 2048;
  const int tid = threadIdx.x;
  float4 a = *(const float4*)(xr + tid * 8);
  float4 b = *(const float4*)(xr + tid * 8 + 4);
  float s  = a.x + a.y + a.z + a.w + b.x + b.y + b.z + b.w;
  float ss = a.x*a.x + a.y*a.y + a.z*a.z + a.w*a.w
           + b.x*b.x + b.y*b.y + b.z*b.z + b.w*b.w;
  #pragma unroll
  for (int off = 1; off < 64; off <<= 1) { s += __shfl_xor(s, off); ss += __shfl_xor(ss, off); }
  __shared__ float red[8];
  if ((tid & 63) == 0) { red[tid >> 6] = s; red[4 + (tid >> 6)] = ss; }
  __syncthreads();
  s  = red[0] + red[1] + red[2] + red[3];
  ss = red[4] + red[5] + red[6] + red[7];
  const float mu = s * (1.0f / 2048.0f);
  const float rs = rsqrtf(ss * (1.0f / 2048.0f) - mu * mu + 1e-5f);
  const float v[8] = {a.x, a.y, a.z, a.w, b.x, b.y, b.z, b.w};
  u16x8 o;
  #pragma unroll
  for (int j = 0; j < 8; ++j) {
    const int col = tid * 8 + j;
    o[j] = f2b((v[j] - mu) * rs * gamma[col] + beta[col]);
  }
  *(u16x8*)(out + row * 2048 + tid * 8) = o;
}

// ---------------------------------------------------------------------------
// ksum[d_row] = sum_s kT[d_row][s]
// ---------------------------------------------------------------------------
__global__ __launch_bounds__(256) void ksum_kernel(
    const u16* __restrict__ kT, float* __restrict__ ksum)
{
  const int gw = blockIdx.x * 4 + (threadIdx.x >> 6);
  const int lane = threadIdx.x & 63;
  const u16* r = kT + (long)gw * 2048;
  float s = 0.f;
  #pragma unroll
  for (int j = 0; j < 4; ++j) {
    u16x8 v = *(const u16x8*)(r + j * 512 + lane * 8);
    #pragma unroll
    for (int e = 0; e < 8; ++e) s += b2f(v[e]);
  }
  #pragma unroll
  for (int off = 1; off < 64; off <<= 1) s += __shfl_xor(s, off);
  if (lane == 0) ksum[gw] = s;
}

// ---------------------------------------------------------------------------
// den[b][h][s] = dot(q[b][s][h*128:], ksum[b][h][:])
// ---------------------------------------------------------------------------
__global__ __launch_bounds__(256) void den_kernel(
    const u16* __restrict__ q, const float* __restrict__ ksum, float* __restrict__ den)
{
  const long m = blockIdx.x;            // b*2048 + s
  const int tid = threadIdx.x;
  const int b = (int)(m >> 11);
  const int h = tid >> 4;
  const int dl = (tid & 15) * 8;
  const u16* qr = q + m * 2048 + h * 128 + dl;
  const float* ks = ksum + ((long)b * 16 + h) * 128 + dl;
  u16x8 v = *(const u16x8*)qr;
  float s = 0.f;
  #pragma unroll
  for (int e = 0; e < 8; ++e) s += b2f(v[e]) * ks[e];
  #pragma unroll
  for (int off = 1; off < 16; off <<= 1) s += __shfl_xor(s, off);
  if ((tid & 15) == 0) den[((long)b * 16 + h) * 2048 + (m & 2047)] = s;
}

// ---------------------------------------------------------------------------
// kv split-K reduce: out_bf16[i] = sum_{p<8} partial[p][i]
// ---------------------------------------------------------------------------
__global__ __launch_bounds__(256) void kvreduce_kernel(
    const float* __restrict__ p, u16* __restrict__ out)
{
  long i = ((long)blockIdx.x * 256 + threadIdx.x) * 4;
  float4 s = *(const float4*)(p + i);
  #pragma unroll
  for (int j = 1; j < 8; ++j) {
    float4 v = *(const float4*)(p + (long)j * 1048576 + i);
    s.x += v.x; s.y += v.y; s.z += v.z; s.w += v.w;
  }
  u16x4 o; o[0] = f2b(s.x); o[1] = f2b(s.y); o[2] = f2b(s.z); o[3] = f2b(s.w);
  *(u16x4*)(out + i) = o;
}

// ---------------------------------------------------------------------------
// RANK split-K reduce (f32 partials): out = sum_{p<NP} P[p] (+bias) (+old)
// ---------------------------------------------------------------------------
template<int NP, int OUTF32, int ACC>
__global__ __launch_bounds__(256) void rankreduce_kernel(
    const float* __restrict__ p, const float* __restrict__ bias, void* out)
{
  long i = ((long)blockIdx.x * 256 + threadIdx.x) * 4;
  float4 s = *(const float4*)(p + i);
  #pragma unroll
  for (int j = 1; j < NP; ++j) {
    float4 v = *(const float4*)(p + (long)j * 2097152 + i);
    s.x += v.x; s.y += v.y; s.z += v.z; s.w += v.w;
  }
  if (bias) {
    const int col = (int)(i & 255);
    s.x += bias[col]; s.y += bias[col + 1]; s.z += bias[col + 2]; s.w += bias[col + 3];
  }
  if (ACC) {
    float4 o = *(const float4*)((const float*)out + i);
    s.x += o.x; s.y += o.y; s.z += o.z; s.w += o.w;
  }
  if (OUTF32) {
    *(float4*)((float*)out + i) = s;
  } else {
    u16x4 o; o[0] = f2b(s.x); o[1] = f2b(s.y); o[2] = f2b(s.z); o[3] = f2b(s.w);
    *(u16x4*)((u16*)out + i) = o;
  }
}

// ---------------------------------------------------------------------------
// RANK reduce, 8 bf16 partials -> bf16 out (+bias)
// ---------------------------------------------------------------------------
__global__ __launch_bounds__(256) void rankreduce8b_kernel(
    const u16* __restrict__ p, const float* __restrict__ bias, u16* __restrict__ out)
{
  long i = ((long)blockIdx.x * 256 + threadIdx.x) * 4;
  float4 s = {0.f, 0.f, 0.f, 0.f};
  #pragma unroll
  for (int j = 0; j < 8; ++j) {
    u16x4 v = *(const u16x4*)(p + (long)j * 2097152 + i);
    s.x += b2f(v[0]); s.y += b2f(v[1]); s.z += b2f(v[2]); s.w += b2f(v[3]);
  }
  const int col = (int)(i & 255);
  s.x += bias[col]; s.y += bias[col + 1]; s.z += bias[col + 2]; s.w += bias[col + 3];
  u16x4 o; o[0] = f2b(s.x); o[1] = f2b(s.y); o[2] = f2b(s.z); o[3] = f2b(s.w);
  *(u16x4*)(out + i) = o;
}

// ---------------------------------------------------------------------------
// 256x128-tile bt-GEMM (ring-3 counted vmcnt + swz64):
// grid (M/256, N/128). K % 32 == 0. 8 waves = 4M x 2N, acc[4][4] = 64 VGPR.
// ---------------------------------------------------------------------------
template<int OUTMODE, int RESID>
__global__ __launch_bounds__(512, 4) void btg128_kernel(
    const u16* __restrict__ A, const u16* __restrict__ Bt, void* Cv,
    const float* __restrict__ bias, const float* resid,
    int K, int lda, int ldb, int ldc)
{
  __shared__ char lds[73728];                // 3 regions x (A 16KB + B 8KB)
  const int tid = threadIdx.x;
  const int wave = tid >> 6, lane = tid & 63;
  const int lr = lane & 15, lk = lane >> 4;
  const int wr = wave >> 1, wc = wave & 1;   // 4M x 2N
  const char* Ab = (const char*)(A + (long)blockIdx.x * 256 * lda);
  const char* Bb = (const char*)(Bt + (long)blockIdx.y * 128 * ldb);
  const long ldaB = (long)lda * 2, ldbB = (long)ldb * 2;

  long srcA[2], srcB;
  int  dstA[2], dstB;
  #pragma unroll
  for (int j = 0; j < 2; ++j) {
    const int c = j * 512 + tid;            // A chunk 0..1023
    const int row = c >> 2;                 // 0..255 (64B rows)
    const int cb = (c & 3) * 16;
    srcA[j] = (long)row * ldaB + (cb ^ swz64(row));
    dstA[j] = c * 16;
  }
  {
    const int c = tid;                      // B chunk 0..511
    const int row = c >> 2;                 // 0..127
    const int cb = (c & 3) * 16;
    srcB = (long)row * ldbB + (cb ^ swz64(row));
    dstB = c * 16;
  }
  const int swzR = (lk * 16) ^ swz64(lr);

  f32x4 acc[4][4] = {};

  #define STGG(s, reg)                                                     \
    {                                                                      \
      char* R_ = lds + (reg) * 24576;                                      \
      const long colB_ = (long)(s) * 64;                                   \
      _Pragma("unroll")                                                    \
      for (int j = 0; j < 2; ++j)                                          \
        gload16(Ab + srcA[j] + colB_, R_ + dstA[j]);                       \
      gload16(Bb + srcB + colB_, R_ + 16384 + dstB);                       \
    }

  const int S = K >> 5;
  STGG(0, 0);
  if (S > 1) STGG(1, 1);
  if (S > 2) STGG(2, 2);
  int cur = 0;
  for (int s = 0; s < S; ++s) {
    if (s + 2 < S) { VMCNT(6); } else if (s + 1 < S) { VMCNT(3); } else { VMCNT(0); }
    SBAR(); SCHED0();
    {
      const char* R_ = lds + cur * 24576;
      bf16x8 af[4], bf[4];
      #pragma unroll
      for (int m = 0; m < 4; ++m)
        af[m] = *(const bf16x8*)(R_ + (wr * 64 + m * 16 + lr) * 64 + swzR);
      #pragma unroll
      for (int n = 0; n < 4; ++n)
        bf[n] = *(const bf16x8*)(R_ + 16384 + (wc * 64 + n * 16 + lr) * 64 + swzR);
      __builtin_amdgcn_s_setprio(1);
      #pragma unroll
      for (int m = 0; m < 4; ++m)
        #pragma unroll
        for (int n = 0; n < 4; ++n)
          acc[m][n] = __builtin_amdgcn_mfma_f32_16x16x32_bf16(af[m], bf[n], acc[m][n], 0, 0, 0);
      __builtin_amdgcn_s_setprio(0);
    }
    SBAR(); SCHED0();                        // all waves done reading region cur
    if (s + 3 < S) STGG(s + 3, cur);         // (s+3)%3 == s%3 == cur
    cur = (cur == 2) ? 0 : cur + 1;
  }
  #undef STGG

  #pragma unroll
  for (int m = 0; m < 4; ++m) {
    #pragma unroll
    for (int n = 0; n < 4; ++n) {
      const int gm0 = blockIdx.x * 256 + wr * 64 + m * 16 + lk * 4;
      const int gn  = blockIdx.y * 128 + wc * 64 + n * 16 + lr;
      float v4[4];
      #pragma unroll
      for (int i = 0; i < 4; ++i) {
        float val = acc[m][n][i];
        if (bias) val += bias[gn];
        if (RESID) val += resid[(long)(gm0 + i) * ldc + gn];
        v4[i] = val;
      }
      if (OUTMODE == 0) {
        u16* C = (u16*)Cv;
        #pragma unroll
        for (int i = 0; i < 4; ++i) C[(long)(gm0 + i) * ldc + gn] = f2b(v4[i]);
      } else {
        float* C = (float*)Cv;
        #pragma unroll
        for (int i = 0; i < 4; ++i) C[(long)(gm0 + i) * ldc + gn] = v4[i];
      }
    }
  }
}

// ---------------------------------------------------------------------------
// Fused q/k/v GEMM (ring-3 + swz64): grid (32,16,3).
// ---------------------------------------------------------------------------
__global__ __launch_bounds__(512, 4) void qkv256_kernel(
    const u16* __restrict__ A, const u16* __restrict__ Wt0,
    u16* __restrict__ Qout, u16* __restrict__ Kout, u16* __restrict__ Vout,
    const float* __restrict__ bq, const float* __restrict__ bk,
    const float* __restrict__ bv)
{
  __shared__ char lds[73728];                // 3 regions x (A 16KB + B 8KB)
  const int tid = threadIdx.x;
  const int wave = tid >> 6, lane = tid & 63;
  const int lr = lane & 15, lk = lane >> 4;
  const int wr = wave >> 1, wc = wave & 1;   // 4M x 2N
  const int z = blockIdx.z;
  const char* Ab = (const char*)(A + (long)blockIdx.x * 256 * 2048);
  const char* Bb = (const char*)(Wt0 + (long)z * 4194304 + (long)blockIdx.y * 128 * 2048);

  long srcA[2], srcB;
  int  dstA[2], dstB;
  #pragma unroll
  for (int j = 0; j < 2; ++j) {
    const int c = j * 512 + tid;            // A chunk 0..1023
    const int row = c >> 2;                 // 0..255 (64B rows)
    const int cb = (c & 3) * 16;
    srcA[j] = (long)row * 4096 + (cb ^ swz64(row));
    dstA[j] = c * 16;
  }
  {
    const int c = tid;                      // B chunk 0..511
    const int row = c >> 2;                 // 0..127
    const int cb = (c & 3) * 16;
    srcB = (long)row * 4096 + (cb ^ swz64(row));
    dstB = c * 16;
  }
  const int swzR = (lk * 16) ^ swz64(lr);

  f32x4 acc[4][4] = {};

  #define STGQ(s, reg)                                                     \
    {                                                                      \
      char* R_ = lds + (reg) * 24576;                                      \
      const long colB_ = (long)(s) * 64;                                   \
      _Pragma("unroll")                                                    \
      for (int j = 0; j < 2; ++j)                                          \
        gload16(Ab + srcA[j] + colB_, R_ + dstA[j]);                       \
      gload16(Bb + srcB + colB_, R_ + 16384 + dstB);                       \
    }

  const int S = 64;                          // K=2048 / 32
  STGQ(0, 0); STGQ(1, 1); STGQ(2, 2);        // 9 loads/thread outstanding
  int cur = 0;
  for (int s = 0; s < S; ++s) {
    if (s + 2 < S) { VMCNT(6); } else if (s + 1 < S) { VMCNT(3); } else { VMCNT(0); }
    SBAR(); SCHED0();
    {
      const char* R_ = lds + cur * 24576;
      bf16x8 af[4], bf[4];
      #pragma unroll
      for (int m = 0; m < 4; ++m)
        af[m] = *(const bf16x8*)(R_ + (wr * 64 + m * 16 + lr) * 64 + swzR);
      #pragma unroll
      for (int n = 0; n < 4; ++n)
        bf[n] = *(const bf16x8*)(R_ + 16384 + (wc * 64 + n * 16 + lr) * 64 + swzR);
      __builtin_amdgcn_s_setprio(1);
      #pragma unroll
      for (int m = 0; m < 4; ++m)
        #pragma unroll
        for (int n = 0; n < 4; ++n)
          acc[m][n] = __builtin_amdgcn_mfma_f32_16x16x32_bf16(af[m], bf[n], acc[m][n], 0, 0, 0);
      __builtin_amdgcn_s_setprio(0);
    }
    SBAR(); SCHED0();
    if (s + 3 < S) STGQ(s + 3, cur);
    cur = (cur == 2) ? 0 : cur + 1;
  }
  #undef STGQ

  const float* bias = (z == 0) ? bq : (z == 1) ? bk : bv;
  #pragma unroll
  for (int m = 0; m < 4; ++m) {
    #pragma unroll
    for (int n = 0; n < 4; ++n) {
      const int gm0 = blockIdx.x * 256 + wr * 64 + m * 16 + lk * 4;
      const int gn  = blockIdx.y * 128 + wc * 64 + n * 16 + lr;
      float v4[4];
      #pragma unroll
      for (int i = 0; i < 4; ++i) {
        float val = acc[m][n][i] + bias[gn];
        if (z != 2)  // q,k: elu(x)+1
          val = (val > 0.f) ? (val + 1.f) : __builtin_exp2f(val * 1.4426950408889634f);
        v4[i] = val;
      }
      if (z == 0) {
        #pragma unroll
        for (int i = 0; i < 4; ++i) Qout[(long)(gm0 + i) * 2048 + gn] = f2b(v4[i]);
      } else {
        u16* C = (z == 1) ? Kout : Vout;     // transposed (B,H,HD,S)
        const int b = gm0 >> 11, s = gm0 & 2047;
        const int h = gn >> 7,  d = gn & 127;
        u16x4 p;
        p[0] = f2b(v4[0]); p[1] = f2b(v4[1]); p[2] = f2b(v4[2]); p[3] = f2b(v4[3]);
        *(u16x4*)(C + (long)((b * 16 + h) * 128 + d) * 2048 + s) = p;
      }
    }
  }
}

// ---------------------------------------------------------------------------
// 128x128-tile z-batched bt-GEMM: ring + reg-dbuf + swz64 (tail kernels).
// Requires K % 64 == 0, K >= 128.
// ---------------------------------------------------------------------------
template<int ACT, int OUTMODE, int RESID, int ACCUM, int DIVDEN>
__global__ __launch_bounds__(256) void btgemm_kernel(
    const u16* __restrict__ A, const u16* __restrict__ Bt, void* Cv,
    const float* __restrict__ bias, const float* resid, const float* __restrict__ den,
    int M, int N, int K, int lda, int ldb, int ldc, int ZMOD,
    long sAh, long sAl, long sBh, long sBl, long sCh, long sCl, long sDh, long sDl)
{
  __shared__ char lds[65536];
  const int tid = threadIdx.x;
  const int wave = tid >> 6, lane = tid & 63;
  const int lr = lane & 15, lk = lane >> 4;
  const int wr = wave >> 1, wc = wave & 1;
  const int z = blockIdx.z;
  const int zh = z / ZMOD, zl = z % ZMOD;
  const char* Ab = (const char*)(A + zh * sAh + zl * sAl + (long)blockIdx.x * 128 * lda);
  const char* Bb = (const char*)(Bt + zh * sBh + zl * sBl + (long)blockIdx.y * 128 * ldb);
  const long ldaB = (long)lda * 2, ldbB = (long)ldb * 2;

  long srcA[2], srcB[2];
  int  dstO[2];
  #pragma unroll
  for (int j = 0; j < 2; ++j) {
    const int c = j * 256 + tid;            // chunk 0..511
    const int row = c >> 2;                 // 0..127 (64B rows)
    const int cb = (c & 3) * 16;
    srcA[j] = (long)row * ldaB + (cb ^ swz64(row));
    srcB[j] = (long)row * ldbB + (cb ^ swz64(row));
    dstO[j] = c * 16;
  }
  const int swzR = (lk * 16) ^ swz64(lr);

  f32x4 acc[4][4] = {};
  bf16x8 a_af[4], a_bf[4], b_af[4], b_bf[4];

  #define STG7(s)                                                          \
    { char* R_ = lds + ((s) & 3) * 16384; const long cB_ = (long)(s) * 64; \
      _Pragma("unroll") for (int j = 0; j < 2; ++j) {                      \
        gload16(Ab + srcA[j] + cB_, R_ + dstO[j]);                         \
        gload16(Bb + srcB[j] + cB_, R_ + 8192 + dstO[j]); } }

  #define RD7(P, s)                                                       \
    { const char* R_ = lds + ((s) & 3) * 16384;                            \
      _Pragma("unroll") for (int m = 0; m < 4; ++m)                        \
        P##af[m] = *(const bf16x8*)(R_ + (wr * 64 + m * 16 + lr) * 64 + swzR); \
      _Pragma("unroll") for (int n = 0; n < 4; ++n)                        \
        P##bf[n] = *(const bf16x8*)(R_ + 8192 + (wc * 64 + n * 16 + lr) * 64 + swzR); }

  #define MM7(P)                                                           \
    { __builtin_amdgcn_s_setprio(1);                                       \
      _Pragma("unroll") for (int m = 0; m < 4; ++m)                        \
        _Pragma("unroll") for (int n = 0; n < 4; ++n)                      \
          acc[m][n] = __builtin_amdgcn_mfma_f32_16x16x32_bf16(P##af[m], P##bf[n], acc[m][n], 0, 0, 0); \
      __builtin_amdgcn_s_setprio(0); }

  const int S = K >> 5;                     // even, >= 4
  STG7(0); STG7(1); STG7(2);
  VMCNT(8); SBAR(); SCHED0();
  RD7(a_, 0);
  for (int s = 0; s < S - 2; s += 2) {
    VMCNT(4); SBAR(); SCHED0();
    RD7(b_, s + 1);
    if (s + 3 < S) STG7(s + 3);
    SCHED0();
    MM7(a_);
    VMCNT(4); SBAR(); SCHED0();
    RD7(a_, s + 2);
    if (s + 4 < S) STG7(s + 4);
    SCHED0();
    MM7(b_);
  }
  VMCNT(0); SBAR(); SCHED0();
  RD7(b_, S - 1);
  SCHED0();
  MM7(a_);
  MM7(b_);
  #undef STG7
  #undef RD7
  #undef MM7

  const long cbase = (long)zh * sCh + (long)zl * sCl;
  #pragma unroll
  for (int m = 0; m < 4; ++m) {
    #pragma unroll
    for (int n = 0; n < 4; ++n) {
      const int gm0 = blockIdx.x * 128 + wr * 64 + m * 16 + lk * 4;
      const int gn  = blockIdx.y * 128 + wc * 64 + n * 16 + lr;
      float v4[4];
      #pragma unroll
      for (int i = 0; i < 4; ++i) {
        float val = acc[m][n][i];
        if (bias) val += bias[gn];
        if (ACT == 1) val = (val > 0.f) ? (val + 1.f) : __builtin_exp2f(val * 1.4426950408889634f);
        if (ACT == 2) val = gelu_f(val);
        if (DIVDEN) val = val / (den[(long)zh * sDh + (long)zl * sDl + gm0 + i] + 1e-6f);
        if (RESID) val += resid[cbase + (long)(gm0 + i) * ldc + gn];
        if (ACCUM) val += ((const float*)Cv)[cbase + (long)(gm0 + i) * ldc + gn];
        v4[i] = val;
      }
      if (OUTMODE == 0) {
        u16* C = (u16*)Cv;
        #pragma unroll
        for (int i = 0; i < 4; ++i) C[cbase + (long)(gm0 + i) * ldc + gn] = f2b(v4[i]);
      } else if (OUTMODE == 1) {
        float* C = (float*)Cv;
        #pragma unroll
        for (int i = 0; i < 4; ++i) C[cbase + (long)(gm0 + i) * ldc + gn] = v4[i];
      } else {
        u16* C = (u16*)Cv;
        const int b = gm0 >> 11, s = gm0 & 2047;
        const int h = gn >> 7,  d = gn & 127;
        u16x4 p;
        p[0] = f2b(v4[0]); p[1] = f2b(v4[1]); p[2] = f2b(v4[2]); p[3] = f2b(v4[3]);
        *(u16x4*)(C + (long)((b * 16 + h) * 128 + d) * 2048 + s) = p;
      }
    }
  }
}

// ---------------------------------------------------------------------------
// Fused FFN middle v5: 64-row M-tile, hg split 8 (grid 128x8), bf16 partials.
// 512 thr, LDS 72KB, 2 blocks/CU.
// ---------------------------------------------------------------------------
__global__ __launch_bounds__(512, 4) void ffnmid_kernel(
    const u16* __restrict__ T1,   // [8192][256] bf16
    const u16* __restrict__ W2T,  // [8192][256] bf16 (rows = HID)
    const u16* __restrict__ W3T,  // [256][8192] bf16 (rows = rank)
    const float* __restrict__ b2, // [8192]
    u16* __restrict__ RP)         // [8][8192][256] bf16 partials
{
  __shared__ char Wb[2][32768];   // W2s [32][512B] swz(r&7)<<4 ; W3s [256][64B] swz(r&3)<<4
  __shared__ char Ps[8192];       // [64][128B] swz(m&7)<<4, cols 0..63B used
  const int tid = threadIdx.x;
  const int wave = tid >> 6, lane = tid & 63;
  const int lr = lane & 15, lk = lane >> 4;
  const int wn  = wave & 1;       // stage-1 A(W2) n-frag (n0 = wn*16)
  const int wm  = wave >> 1;      // stage-1 B(T1) m-frag (m0 = wm*16)
  const int wmm = wave & 1;       // stage-2 m-group (m0 = wmm*32)
  const int wrr = wave >> 1;      // stage-2 r-group (r0 = wrr*64)
  const int mb = blockIdx.x, hg = blockIdx.y;

  // T1 fragment -> registers (B-operand layout: row=lr, k=lk*8+e), once.
  bf16x8 t1r[8];
  {
    const long row = (long)mb * 64 + wm * 16 + lr;
    #pragma unroll
    for (int kx = 0; kx < 8; ++kx)
      t1r[kx] = *(const bf16x8*)(T1 + row * 256 + kx * 32 + lk * 8);
  }

  #define STG_SLICE(it, buf)                                               \
    {                                                                      \
      const long h0_ = (long)hg * 1024 + (long)(it) * 32;                  \
      const char* s2_ = (const char*)W2T + h0_ * 512;                      \
      _Pragma("unroll")                                                    \
      for (int j = 0; j < 2; ++j) {                                        \
        const int c = j * 512 + tid;             /* 0..1023 */             \
        const int r = c >> 5;                    /* 0..31  */              \
        const int cb = (c & 31) * 16;                                      \
        gload16(s2_ + r * 512 + (cb ^ ((r & 7) << 4)), Wb[buf] + c * 16);  \
      }                                                                    \
      _Pragma("unroll")                                                    \
      for (int j = 0; j < 2; ++j) {                                        \
        const int c = j * 512 + tid;             /* 0..1023 */             \
        const int r = c >> 2;                    /* 0..255 */              \
        const int cb = (c & 3) * 16;                                       \
        gload16((const char*)W3T + (long)r * 16384 + h0_ * 2 +             \
                    (cb ^ ((r & 3) << 4)),                                 \
                Wb[buf] + 16384 + c * 16);                                 \
      }                                                                    \
    }

  const float* bbase = b2 + (long)hg * 1024 + wn * 16 + lk * 4;
  float4 bias = *(const float4*)bbase;
  STG_SLICE(0, 0);
  VMCNT(0); SBAR();

  f32x4 acc2[2][4] = {};

  for (int it = 0; it < 32; ++it) {
    const int cur = it & 1;
    const char* W2s = Wb[cur];
    const char* W3s = Wb[cur] + 16384;

    float4 bias_n = bias;
    if (it + 1 < 32) {
      STG_SLICE(it + 1, cur ^ 1);
      bias_n = *(const float4*)(bbase + (it + 1) * 32);
    }
    SCHED0();

    // stage-1: D(n,m) = W2slice @ T1^T   (32 x 64, K=256), T1 in regs
    f32x4 p = {};
    #pragma unroll
    for (int kx = 0; kx < 8; ++kx) {
      const int nn = wn * 16 + lr;           // A row
      bf16x8 w2f = *(const bf16x8*)(W2s + nn * 512 + (((kx * 32 + lk * 8) * 2) ^ ((nn & 7) << 4)));
      p = __builtin_amdgcn_mfma_f32_16x16x32_bf16(w2f, t1r[kx], p, 0, 0, 0);
    }
    // gelu + vector write: thread holds (n = wn*16+lk*4+i, m = wm*16+lr)
    {
      const int m = wm * 16 + lr;
      u16x4 pk;
      pk[0] = f2b(gelu_f(p[0] + bias.x));
      pk[1] = f2b(gelu_f(p[1] + bias.y));
      pk[2] = f2b(gelu_f(p[2] + bias.z));
      pk[3] = f2b(gelu_f(p[3] + bias.w));
      *(u16x4*)(Ps + m * 128 + ((wn * 32 + lk * 8) ^ ((m & 7) << 4))) = pk;
    }
    LGKMCNT0();   // cross-wave ds_write -> ds_read: drain before barrier
    SBAR();

    // stage-2: acc2 += P @ W3slice^T   (64 x 256, K=32), 2m x 4r frags
    {
      bf16x8 af[2], bf[4];
      #pragma unroll
      for (int fm = 0; fm < 2; ++fm) {
        const int m = wmm * 32 + fm * 16 + lr;
        af[fm] = *(const bf16x8*)(Ps + m * 128 + ((lk * 16) ^ ((m & 7) << 4)));
      }
      #pragma unroll
      for (int fr = 0; fr < 4; ++fr) {
        const int r = wrr * 64 + fr * 16 + lr;
        bf[fr] = *(const bf16x8*)(W3s + r * 64 + ((lk * 16) ^ ((r & 3) << 4)));
      }
      __builtin_amdgcn_s_setprio(1);
      #pragma unroll
      for (int fm = 0; fm < 2; ++fm)
        #pragma unroll
        for (int fr = 0; fr < 4; ++fr)
          acc2[fm][fr] = __builtin_amdgcn_mfma_f32_16x16x32_bf16(af[fm], bf[fr], acc2[fm][fr], 0, 0, 0);
      __builtin_amdgcn_s_setprio(0);
    }
    bias = bias_n;
    VMCNT(0);   // next slice + bias landed (overlapped with compute above)
    SBAR();     // Ps/W3s reads consumed -> safe to overwrite next iter
  }
  #undef STG_SLICE

  // epilogue: partial bf16 [64][256]
  u16* out = RP + (long)hg * 2097152 + (long)mb * 64 * 256;
  #pragma unroll
  for (int fm = 0; fm < 2; ++fm) {
    #pragma unroll
    for (int fr = 0; fr < 4; ++fr) {
      const int r = wrr * 64 + fr * 16 + lr;
      #pragma unroll
      for (int i = 0; i < 4; ++i) {
        const int m = wmm * 32 + fm * 16 + lk * 4 + i;
        out[(long)m * 256 + r] = f2b(acc2[fm][fr][i]);
      }
    }
  }
}

// ---------------------------------------------------------------------------
extern "C" void kernel_launch(void* const* d_in, const int* in_sizes, int n_in,
                              void* d_out, int out_size, void* d_ws, size_t ws_size,
                              hipStream_t stream) {
  const float* x   = (const float*)d_in[0];
  const float* Wq  = (const float*)d_in[1];
  const float* bq  = (const float*)d_in[2];
  const float* Wk  = (const float*)d_in[3];
  const float* bk  = (const float*)d_in[4];
  const float* Wv  = (const float*)d_in[5];
  const float* bv  = (const float*)d_in[6];
  const float* Wo  = (const float*)d_in[7];
  const float* bo  = (const float*)d_in[8];
  const float* g1  = (const float*)d_in[9];
  const float* be1 = (const float*)d_in[10];
  const float* g2  = (const float*)d_in[11];
  const float* be2 = (const float*)d_in[12];
  const float* W1  = (const float*)d_in[13];
  const float* b1  = (const float*)d_in[14];
  const float* W2  = (const float*)d_in[15];
  const float* b2  = (const float*)d_in[16];
  const float* W3  = (const float*)d_in[17];
  const float* b3  = (const float*)d_in[18];
  const float* W4  = (const float*)d_in[19];
  const float* b4  = (const float*)d_in[20];
  float* xout = (float*)d_out;
  char* ws = (char*)d_ws;

  // workspace layout (bytes); total ~172.6 MB
  constexpr long DD2 = 2048L * 2048 * 2;          // 8 MB
  constexpr size_t oWqT = 0;
  constexpr size_t oWkT = oWqT + DD2;
  constexpr size_t oWvT = oWkT + DD2;
  constexpr size_t oWoT = oWvT + DD2;
  constexpr size_t oW1T = oWoT + DD2;             // 256x2048 bf16 (1 MB)
  constexpr size_t oW2T = oW1T + 256L * 2048 * 2; // 8192x256 bf16 (4 MB)
  constexpr size_t oW3T = oW2T + 8192L * 256 * 2; // 256x8192 bf16 (4 MB)
  constexpr size_t oW4T = oW3T + 256L * 8192 * 2; // 2048x256 bf16 (1 MB)
  constexpr size_t oH1  = oW4T + 2048L * 256 * 2; // 32MB: h1 / kvpart / attnN / t1-partials
  constexpr size_t oQ   = oH1 + 8192L * 2048 * 2; // 32MB: q / h2 / t3b
  constexpr size_t oKT  = oQ  + 8192L * 2048 * 2; // 32MB: kT / t1
  constexpr size_t oVT  = oKT + 8192L * 2048 * 2; // 32MB: vT / ffn partials (bf16 x8)
  constexpr size_t oKVT = oVT + 8192L * 2048 * 2; // 64x128x128 bf16 (2MB)
  constexpr size_t oKS  = oKVT + 64L * 128 * 128 * 2;
  constexpr size_t oDEN = oKS + 64L * 128 * 4;

  u16* WqT = (u16*)(ws + oWqT);
  u16* WkT = (u16*)(ws + oWkT);
  u16* WvT = (u16*)(ws + oWvT);
  u16* WoT = (u16*)(ws + oWoT);
  u16* W1T = (u16*)(ws + oW1T);
  u16* W2T = (u16*)(ws + oW2T);
  u16* W3T = (u16*)(ws + oW3T);
  u16* W4T = (u16*)(ws + oW4T);
  u16* H1    = (u16*)(ws + oH1);    // h1; kv partials; attnN; t1 split-K partials
  float* KVP = (float*)(ws + oH1);
  float* RP1 = (float*)(ws + oH1);  // t1 partials [4][8192][256] f32
  u16* Qb    = (u16*)(ws + oQ);     // q; h2
  u16* T3B   = (u16*)(ws + oQ + 8L * 1024 * 1024); // t3 bf16 (4MB; h2 dead)
  u16* KT    = (u16*)(ws + oKT);    // kT; then t1
  u16* T1    = (u16*)(ws + oKT);
  u16* VT    = (u16*)(ws + oVT);    // vT; then ffn partials
  u16* RPF   = (u16*)(ws + oVT);    // ffn partials [8][8192][256] bf16 (32MB)
  u16* KVT = (u16*)(ws + oKVT);
  float* KS  = (float*)(ws + oKS);
  float* DEN = (float*)(ws + oDEN);
  u16* H2  = Qb;

  const dim3 tb32(32, 8);
  tpose_f32_bf16_kernel<<<dim3(64, 64), tb32, 0, stream>>>(Wq, WqT, 2048, 2048);
  tpose_f32_bf16_kernel<<<dim3(64, 64), tb32, 0, stream>>>(Wk, WkT, 2048, 2048);
  tpose_f32_bf16_kernel<<<dim3(64, 64), tb32, 0, stream>>>(Wv, WvT, 2048, 2048);
  tpose_f32_bf16_kernel<<<dim3(64, 64), tb32, 0, stream>>>(Wo, WoT, 2048, 2048);
  tpose_f32_bf16_kernel<<<dim3(8, 64),  tb32, 0, stream>>>(W1, W1T, 2048, 256);
  tpose_f32_bf16_kernel<<<dim3(256, 8), tb32, 0, stream>>>(W2, W2T, 256, 8192);
  tpose_f32_bf16_kernel<<<dim3(8, 256), tb32, 0, stream>>>(W3, W3T, 8192, 256);
  tpose_f32_bf16_kernel<<<dim3(64, 8),  tb32, 0, stream>>>(W4, W4T, 256, 2048);

  // h1 = LN1(x)
  ln_bf16_kernel<<<8192, 256, 0, stream>>>(x, g1, be1, H1);

  // fused q,k,v projections: ring-3 + swz64, 2 blocks/CU, grid (32,16,3)
  qkv256_kernel<<<dim3(32, 16, 3), 512, 0, stream>>>(
      H1, WqT, Qb, KT, VT, bq, bk, bv);

  // ksum over S, den = q.ksum
  ksum_kernel<<<2048, 256, 0, stream>>>(KT, KS);
  den_kernel<<<8192, 256, 0, stream>>>(Qb, KS, DEN);

  // kv split-K (z = head*8 + K-chunk of 256) -> f32 partials -> reduce
  btgemm_kernel<0, 1, 0, 0, 0><<<dim3(1, 1, 512), 256, 0, stream>>>(
      VT, KT, KVP, nullptr, nullptr, nullptr, 128, 128, 256, 2048, 2048, 128, 8,
      262144, 256, 262144, 256, 16384, 1048576, 0, 0);
  kvreduce_kernel<<<1024, 256, 0, stream>>>(KVP, KVT);

  // num = q @ kvT ; /(den+eps) -> attnN (bf16, (B,S,D), into H1 region)
  btgemm_kernel<0, 0, 0, 0, 1><<<dim3(16, 1, 64), 256, 0, stream>>>(
      Qb, KVT, H1, nullptr, nullptr, DEN, 2048, 128, 128, 2048, 128, 2048, 16,
      4194304, 128, 262144, 16384, 4194304, 128, 32768, 2048);

  // x2 = x + attnN@Wo + bo -> d_out (f32)  [ring-3 + swz64, grid (32,16)]
  btg128_kernel<1, 1><<<dim3(32, 16), 512, 0, stream>>>(
      H1, WoT, xout, bo, x, 2048, 2048, 2048, 2048);

  // h2 = LN2(x2)
  ln_bf16_kernel<<<8192, 256, 0, stream>>>(xout, g2, be2, H2);

  // t1 = h2@W1 + b1 : split-K x4 (K-sub 512) -> reduce bf16
  btgemm_kernel<0, 1, 0, 0, 0><<<dim3(64, 2, 4), 256, 0, stream>>>(
      H2, W1T, RP1, nullptr, nullptr, nullptr, 8192, 256, 512, 2048, 2048, 256, 4,
      0, 512, 0, 512, 0, 2097152, 0, 0);
  rankreduce_kernel<4, 0, 0><<<2048, 256, 0, stream>>>(RP1, b1, T1);

  // fused FFN middle: t3 partials = gelu(t1@W2+b2)@W3, t2 never to HBM
  ffnmid_kernel<<<dim3(128, 8), 512, 0, stream>>>(T1, W2T, W3T, b2, RPF);
  rankreduce8b_kernel<<<2048, 256, 0, stream>>>(RPF, b3, T3B);

  // out = x2 + t3@W4 + b4 (resid = d_out)  [ring-3 + swz64, K=256]
  btg128_kernel<1, 1><<<dim3(32, 16), 512, 0, stream>>>(
      T3B, W4T, xout, b4, xout, 256, 256, 256, 2048);
}

// Round 19
// 663.278 us; speedup vs baseline: 4.8933x; 1.0224x over previous
//
#include <hip/hip_runtime.h>
#include <hip/hip_bf16.h>
#include <cstdint>

typedef float     f32x4  __attribute__((ext_vector_type(4)));
typedef __bf16    bf16x8 __attribute__((ext_vector_type(8)));
typedef unsigned short u16x4 __attribute__((ext_vector_type(4)));
typedef unsigned short u16x8 __attribute__((ext_vector_type(8)));
typedef unsigned short u16;

#define DI __device__ __forceinline__

DI float b2f(u16 u) { union { unsigned int i; float f; } x; x.i = ((unsigned int)u) << 16; return x.f; }
DI u16 f2b(float f) {
  union { float f; unsigned int i; } x; x.f = f;
  return (u16)((x.i + 0x7FFFu + ((x.i >> 16) & 1u)) >> 16);   // RNE
}

// direct global->LDS async copy, 16B per lane
DI void gload16(const void* g, void* l) {
  __builtin_amdgcn_global_load_lds(
      (const __attribute__((address_space(1))) unsigned int*)g,
      (__attribute__((address_space(3))) unsigned int*)l, 16, 0, 0);
}

#define VMCNT(n)  asm volatile("s_waitcnt vmcnt(" #n ")" ::: "memory")
#define LGKMCNT0() asm volatile("s_waitcnt lgkmcnt(0)" ::: "memory")
#define SBAR()    __builtin_amdgcn_s_barrier()
#define SCHED0()  __builtin_amdgcn_sched_barrier(0)

// 64B-row LDS swizzle: slot XOR (r ^ r>>2)&3
DI int swz64(int row) { return ((row ^ (row >> 2)) & 3) << 4; }

DI float gelu_f(float u) {
  const float y = 0.7978845608028654f * (u + 0.044715f * u * u * u);
  const float t = 1.0f - 2.0f / (__builtin_exp2f(y * 2.885390081777927f) + 1.0f);
  return 0.5f * u * (1.0f + t);
}

// ---------------------------------------------------------------------------
// Transpose + fp32->bf16 convert: src (R x C) f32 row-major -> dst (C x R) bf16
// ---------------------------------------------------------------------------
__global__ __launch_bounds__(256) void tpose_f32_bf16_kernel(
    const float* __restrict__ src, u16* __restrict__ dst, int R, int C)
{
  __shared__ float tile[32][33];
  const int c0 = blockIdx.x * 32, r0 = blockIdx.y * 32;
  const int tx = threadIdx.x, ty = threadIdx.y;
  #pragma unroll
  for (int i = 0; i < 4; ++i)
    tile[ty + i * 8][tx] = src[(long)(r0 + ty + i * 8) * C + c0 + tx];
  __syncthreads();
  #pragma unroll
  for (int i = 0; i < 4; ++i)
    dst[(long)(c0 + ty + i * 8) * R + r0 + tx] = f2b(tile[tx][ty + i * 8]);
}

// ---------------------------------------------------------------------------
// LayerNorm (row of 2048) fp32 -> bf16.
// ---------------------------------------------------------------------------
__global__ __launch_bounds__(256) void ln_bf16_kernel(
    const float* __restrict__ x, const float* __restrict__ gamma,
    const float* __restrict__ beta, u16* __restrict__ out)
{
  const long row = blockIdx.x;
  const float* xr = x + row * 2048;
  const int tid = threadIdx.x;
  float4 a = *(const float4*)(xr + tid * 8);
  float4 b = *(const float4*)(xr + tid * 8 + 4);
  float s  = a.x + a.y + a.z + a.w + b.x + b.y + b.z + b.w;
  float ss = a.x*a.x + a.y*a.y + a.z*a.z + a.w*a.w
           + b.x*b.x + b.y*b.y + b.z*b.z + b.w*b.w;
  #pragma unroll
  for (int off = 1; off < 64; off <<= 1) { s += __shfl_xor(s, off); ss += __shfl_xor(ss, off); }
  __shared__ float red[8];
  if ((tid & 63) == 0) { red[tid >> 6] = s; red[4 + (tid >> 6)] = ss; }
  __syncthreads();
  s  = red[0] + red[1] + red[2] + red[3];
  ss = red[4] + red[5] + red[6] + red[7];
  const float mu = s * (1.0f / 2048.0f);
  const float rs = rsqrtf(ss * (1.0f / 2048.0f) - mu * mu + 1e-5f);
  const float v[8] = {a.x, a.y, a.z, a.w, b.x, b.y, b.z, b.w};
  u16x8 o;
  #pragma unroll
  for (int j = 0; j < 8; ++j) {
    const int col = tid * 8 + j;
    o[j] = f2b((v[j] - mu) * rs * gamma[col] + beta[col]);
  }
  *(u16x8*)(out + row * 2048 + tid * 8) = o;
}

// ---------------------------------------------------------------------------
// ksum[d_row] = sum_s kT[d_row][s]
// ---------------------------------------------------------------------------
__global__ __launch_bounds__(256) void ksum_kernel(
    const u16* __restrict__ kT, float* __restrict__ ksum)
{
  const int gw = blockIdx.x * 4 + (threadIdx.x >> 6);
  const int lane = threadIdx.x & 63;
  const u16* r = kT + (long)gw * 2048;
  float s = 0.f;
  #pragma unroll
  for (int j = 0; j < 4; ++j) {
    u16x8 v = *(const u16x8*)(r + j * 512 + lane * 8);
    #pragma unroll
    for (int e = 0; e < 8; ++e) s += b2f(v[e]);
  }
  #pragma unroll
  for (int off = 1; off < 64; off <<= 1) s += __shfl_xor(s, off);
  if (lane == 0) ksum[gw] = s;
}

// ---------------------------------------------------------------------------
// den[b][h][s] = dot(q[b][s][h*128:], ksum[b][h][:])
// ---------------------------------------------------------------------------
__global__ __launch_bounds__(256) void den_kernel(
    const u16* __restrict__ q, const float* __restrict__ ksum, float* __restrict__ den)
{
  const long m = blockIdx.x;            // b*2048 + s
  const int tid = threadIdx.x;
  const int b = (int)(m >> 11);
  const int h = tid >> 4;
  const int dl = (tid & 15) * 8;
  const u16* qr = q + m * 2048 + h * 128 + dl;
  const float* ks = ksum + ((long)b * 16 + h) * 128 + dl;
  u16x8 v = *(const u16x8*)qr;
  float s = 0.f;
  #pragma unroll
  for (int e = 0; e < 8; ++e) s += b2f(v[e]) * ks[e];
  #pragma unroll
  for (int off = 1; off < 16; off <<= 1) s += __shfl_xor(s, off);
  if ((tid & 15) == 0) den[((long)b * 16 + h) * 2048 + (m & 2047)] = s;
}

// ---------------------------------------------------------------------------
// kv split-K reduce: out_bf16[i] = sum_{p<8} partial[p][i]
// ---------------------------------------------------------------------------
__global__ __launch_bounds__(256) void kvreduce_kernel(
    const float* __restrict__ p, u16* __restrict__ out)
{
  long i = ((long)blockIdx.x * 256 + threadIdx.x) * 4;
  float4 s = *(const float4*)(p + i);
  #pragma unroll
  for (int j = 1; j < 8; ++j) {
    float4 v = *(const float4*)(p + (long)j * 1048576 + i);
    s.x += v.x; s.y += v.y; s.z += v.z; s.w += v.w;
  }
  u16x4 o; o[0] = f2b(s.x); o[1] = f2b(s.y); o[2] = f2b(s.z); o[3] = f2b(s.w);
  *(u16x4*)(out + i) = o;
}

// ---------------------------------------------------------------------------
// RANK split-K reduce (f32 partials): out = sum_{p<NP} P[p] (+bias) (+old)
// ---------------------------------------------------------------------------
template<int NP, int OUTF32, int ACC>
__global__ __launch_bounds__(256) void rankreduce_kernel(
    const float* __restrict__ p, const float* __restrict__ bias, void* out)
{
  long i = ((long)blockIdx.x * 256 + threadIdx.x) * 4;
  float4 s = *(const float4*)(p + i);
  #pragma unroll
  for (int j = 1; j < NP; ++j) {
    float4 v = *(const float4*)(p + (long)j * 2097152 + i);
    s.x += v.x; s.y += v.y; s.z += v.z; s.w += v.w;
  }
  if (bias) {
    const int col = (int)(i & 255);
    s.x += bias[col]; s.y += bias[col + 1]; s.z += bias[col + 2]; s.w += bias[col + 3];
  }
  if (ACC) {
    float4 o = *(const float4*)((const float*)out + i);
    s.x += o.x; s.y += o.y; s.z += o.z; s.w += o.w;
  }
  if (OUTF32) {
    *(float4*)((float*)out + i) = s;
  } else {
    u16x4 o; o[0] = f2b(s.x); o[1] = f2b(s.y); o[2] = f2b(s.z); o[3] = f2b(s.w);
    *(u16x4*)((u16*)out + i) = o;
  }
}

// ---------------------------------------------------------------------------
// RANK reduce, 8 bf16 partials -> bf16 out (+bias)
// ---------------------------------------------------------------------------
__global__ __launch_bounds__(256) void rankreduce8b_kernel(
    const u16* __restrict__ p, const float* __restrict__ bias, u16* __restrict__ out)
{
  long i = ((long)blockIdx.x * 256 + threadIdx.x) * 4;
  float4 s = {0.f, 0.f, 0.f, 0.f};
  #pragma unroll
  for (int j = 0; j < 8; ++j) {
    u16x4 v = *(const u16x4*)(p + (long)j * 2097152 + i);
    s.x += b2f(v[0]); s.y += b2f(v[1]); s.z += b2f(v[2]); s.w += b2f(v[3]);
  }
  const int col = (int)(i & 255);
  s.x += bias[col]; s.y += bias[col + 1]; s.z += bias[col + 2]; s.w += bias[col + 3];
  u16x4 o; o[0] = f2b(s.x); o[1] = f2b(s.y); o[2] = f2b(s.z); o[3] = f2b(s.w);
  *(u16x4*)(out + i) = o;
}

// ---------------------------------------------------------------------------
// 256x128-tile bt-GEMM (ring-3 + swz64 + SWAPPED MFMA, round-17 proven -89us):
// mfma(bf, af, acc) -> D(row=n, col=m): thread holds 4 consecutive N at fixed
// M -> float4/u16x4 stores + float4 resid loads along the contiguous N axis.
// Unconditional swap: single MFMA chain, no spill.
// grid (M/256, N/128). K % 32 == 0. 8 waves = 4M x 2N, acc[4][4] = 64 VGPR.
// ---------------------------------------------------------------------------
template<int OUTMODE, int RESID>
__global__ __launch_bounds__(512, 4) void btg128_kernel(
    const u16* __restrict__ A, const u16* __restrict__ Bt, void* Cv,
    const float* __restrict__ bias, const float* resid,
    int K, int lda, int ldb, int ldc)
{
  __shared__ char lds[73728];                // 3 regions x (A 16KB + B 8KB)
  const int tid = threadIdx.x;
  const int wave = tid >> 6, lane = tid & 63;
  const int lr = lane & 15, lk = lane >> 4;
  const int wr = wave >> 1, wc = wave & 1;   // 4M x 2N
  const char* Ab = (const char*)(A + (long)blockIdx.x * 256 * lda);
  const char* Bb = (const char*)(Bt + (long)blockIdx.y * 128 * ldb);
  const long ldaB = (long)lda * 2, ldbB = (long)ldb * 2;

  long srcA[2], srcB;
  int  dstA[2], dstB;
  #pragma unroll
  for (int j = 0; j < 2; ++j) {
    const int c = j * 512 + tid;            // A chunk 0..1023
    const int row = c >> 2;                 // 0..255 (64B rows)
    const int cb = (c & 3) * 16;
    srcA[j] = (long)row * ldaB + (cb ^ swz64(row));
    dstA[j] = c * 16;
  }
  {
    const int c = tid;                      // B chunk 0..511
    const int row = c >> 2;                 // 0..127
    const int cb = (c & 3) * 16;
    srcB = (long)row * ldbB + (cb ^ swz64(row));
    dstB = c * 16;
  }
  const int swzR = (lk * 16) ^ swz64(lr);

  f32x4 acc[4][4] = {};

  #define STGG(s, reg)                                                     \
    {                                                                      \
      char* R_ = lds + (reg) * 24576;                                      \
      const long colB_ = (long)(s) * 64;                                   \
      _Pragma("unroll")                                                    \
      for (int j = 0; j < 2; ++j)                                          \
        gload16(Ab + srcA[j] + colB_, R_ + dstA[j]);                       \
      gload16(Bb + srcB + colB_, R_ + 16384 + dstB);                       \
    }

  const int S = K >> 5;
  STGG(0, 0);
  if (S > 1) STGG(1, 1);
  if (S > 2) STGG(2, 2);
  int cur = 0;
  for (int s = 0; s < S; ++s) {
    if (s + 2 < S) { VMCNT(6); } else if (s + 1 < S) { VMCNT(3); } else { VMCNT(0); }
    SBAR(); SCHED0();
    {
      const char* R_ = lds + cur * 24576;
      bf16x8 af[4], bf[4];
      #pragma unroll
      for (int m = 0; m < 4; ++m)
        af[m] = *(const bf16x8*)(R_ + (wr * 64 + m * 16 + lr) * 64 + swzR);
      #pragma unroll
      for (int n = 0; n < 4; ++n)
        bf[n] = *(const bf16x8*)(R_ + 16384 + (wc * 64 + n * 16 + lr) * 64 + swzR);
      __builtin_amdgcn_s_setprio(1);
      #pragma unroll
      for (int m = 0; m < 4; ++m)
        #pragma unroll
        for (int n = 0; n < 4; ++n)
          acc[m][n] = __builtin_amdgcn_mfma_f32_16x16x32_bf16(bf[n], af[m], acc[m][n], 0, 0, 0);
      __builtin_amdgcn_s_setprio(0);
    }
    SBAR(); SCHED0();                        // all waves done reading region cur
    if (s + 3 < S) STGG(s + 3, cur);         // (s+3)%3 == s%3 == cur
    cur = (cur == 2) ? 0 : cur + 1;
  }
  #undef STGG

  // epilogue (swapped layout): thread holds rows=n (4 consec), col=m
  #pragma unroll
  for (int m = 0; m < 4; ++m) {
    #pragma unroll
    for (int n = 0; n < 4; ++n) {
      const int gm  = blockIdx.x * 256 + wr * 64 + m * 16 + lr;
      const int gn0 = blockIdx.y * 128 + wc * 64 + n * 16 + lk * 4;
      float4 bi = {0.f, 0.f, 0.f, 0.f};
      if (bias) bi = *(const float4*)(bias + gn0);
      float4 v4;
      v4.x = acc[m][n][0] + bi.x; v4.y = acc[m][n][1] + bi.y;
      v4.z = acc[m][n][2] + bi.z; v4.w = acc[m][n][3] + bi.w;
      if (RESID) {
        float4 r = *(const float4*)(resid + (long)gm * ldc + gn0);
        v4.x += r.x; v4.y += r.y; v4.z += r.z; v4.w += r.w;
      }
      if (OUTMODE == 0) {
        u16x4 pk; pk[0] = f2b(v4.x); pk[1] = f2b(v4.y); pk[2] = f2b(v4.z); pk[3] = f2b(v4.w);
        *(u16x4*)((u16*)Cv + (long)gm * ldc + gn0) = pk;
      } else {
        *(float4*)((float*)Cv + (long)gm * ldc + gn0) = v4;
      }
    }
  }
}

// ---------------------------------------------------------------------------
// Q projection (ring-3 + swz64 + SWAPPED MFMA, compile-time separate kernel):
// single MFMA chain -> no spill. Vectorized u16x4 Q stores. grid (32,16).
// ---------------------------------------------------------------------------
__global__ __launch_bounds__(512, 4) void qkvQ_kernel(
    const u16* __restrict__ A, const u16* __restrict__ WqT,
    u16* __restrict__ Qout, const float* __restrict__ bq)
{
  __shared__ char lds[73728];                // 3 regions x (A 16KB + B 8KB)
  const int tid = threadIdx.x;
  const int wave = tid >> 6, lane = tid & 63;
  const int lr = lane & 15, lk = lane >> 4;
  const int wr = wave >> 1, wc = wave & 1;   // 4M x 2N
  const char* Ab = (const char*)(A + (long)blockIdx.x * 256 * 2048);
  const char* Bb = (const char*)(WqT + (long)blockIdx.y * 128 * 2048);

  long srcA[2], srcB;
  int  dstA[2], dstB;
  #pragma unroll
  for (int j = 0; j < 2; ++j) {
    const int c = j * 512 + tid;            // A chunk 0..1023
    const int row = c >> 2;                 // 0..255 (64B rows)
    const int cb = (c & 3) * 16;
    srcA[j] = (long)row * 4096 + (cb ^ swz64(row));
    dstA[j] = c * 16;
  }
  {
    const int c = tid;                      // B chunk 0..511
    const int row = c >> 2;                 // 0..127
    const int cb = (c & 3) * 16;
    srcB = (long)row * 4096 + (cb ^ swz64(row));
    dstB = c * 16;
  }
  const int swzR = (lk * 16) ^ swz64(lr);

  f32x4 acc[4][4] = {};

  #define STGQ1(s, reg)                                                    \
    {                                                                      \
      char* R_ = lds + (reg) * 24576;                                      \
      const long colB_ = (long)(s) * 64;                                   \
      _Pragma("unroll")                                                    \
      for (int j = 0; j < 2; ++j)                                          \
        gload16(Ab + srcA[j] + colB_, R_ + dstA[j]);                       \
      gload16(Bb + srcB + colB_, R_ + 16384 + dstB);                       \
    }

  const int S = 64;                          // K=2048 / 32
  STGQ1(0, 0); STGQ1(1, 1); STGQ1(2, 2);
  int cur = 0;
  for (int s = 0; s < S; ++s) {
    if (s + 2 < S) { VMCNT(6); } else if (s + 1 < S) { VMCNT(3); } else { VMCNT(0); }
    SBAR(); SCHED0();
    {
      const char* R_ = lds + cur * 24576;
      bf16x8 af[4], bf[4];
      #pragma unroll
      for (int m = 0; m < 4; ++m)
        af[m] = *(const bf16x8*)(R_ + (wr * 64 + m * 16 + lr) * 64 + swzR);
      #pragma unroll
      for (int n = 0; n < 4; ++n)
        bf[n] = *(const bf16x8*)(R_ + 16384 + (wc * 64 + n * 16 + lr) * 64 + swzR);
      __builtin_amdgcn_s_setprio(1);
      #pragma unroll
      for (int m = 0; m < 4; ++m)
        #pragma unroll
        for (int n = 0; n < 4; ++n)
          acc[m][n] = __builtin_amdgcn_mfma_f32_16x16x32_bf16(bf[n], af[m], acc[m][n], 0, 0, 0);
      __builtin_amdgcn_s_setprio(0);
    }
    SBAR(); SCHED0();
    if (s + 3 < S) STGQ1(s + 3, cur);
    cur = (cur == 2) ? 0 : cur + 1;
  }
  #undef STGQ1

  // swapped layout: rows = n (4 consec at lk*4), col = m (lr) -> u16x4 along N
  #pragma unroll
  for (int m = 0; m < 4; ++m) {
    #pragma unroll
    for (int n = 0; n < 4; ++n) {
      const int gm  = blockIdx.x * 256 + wr * 64 + m * 16 + lr;
      const int gn0 = blockIdx.y * 128 + wc * 64 + n * 16 + lk * 4;
      float4 bi = *(const float4*)(bq + gn0);
      u16x4 pk;
      #pragma unroll
      for (int i = 0; i < 4; ++i) {
        float val = acc[m][n][i] + ((const float*)&bi)[i];
        val = (val > 0.f) ? (val + 1.f) : __builtin_exp2f(val * 1.4426950408889634f);
        pk[i] = f2b(val);
      }
      *(u16x4*)(Qout + (long)gm * 2048 + gn0) = pk;
    }
  }
}

// ---------------------------------------------------------------------------
// K/V projections (ring-3 + swz64, unswapped chain, transposed stores):
// grid (32,16,2): z=0 -> K (elu+1), z=1 -> V.
// ---------------------------------------------------------------------------
__global__ __launch_bounds__(512, 4) void qkvKV_kernel(
    const u16* __restrict__ A, const u16* __restrict__ Wt0,
    u16* __restrict__ Kout, u16* __restrict__ Vout,
    const float* __restrict__ bk, const float* __restrict__ bv)
{
  __shared__ char lds[73728];                // 3 regions x (A 16KB + B 8KB)
  const int tid = threadIdx.x;
  const int wave = tid >> 6, lane = tid & 63;
  const int lr = lane & 15, lk = lane >> 4;
  const int wr = wave >> 1, wc = wave & 1;   // 4M x 2N
  const int z = blockIdx.z;                  // 0=K, 1=V
  const char* Ab = (const char*)(A + (long)blockIdx.x * 256 * 2048);
  const char* Bb = (const char*)(Wt0 + (long)(z + 1) * 4194304 + (long)blockIdx.y * 128 * 2048);

  long srcA[2], srcB;
  int  dstA[2], dstB;
  #pragma unroll
  for (int j = 0; j < 2; ++j) {
    const int c = j * 512 + tid;            // A chunk 0..1023
    const int row = c >> 2;                 // 0..255 (64B rows)
    const int cb = (c & 3) * 16;
    srcA[j] = (long)row * 4096 + (cb ^ swz64(row));
    dstA[j] = c * 16;
  }
  {
    const int c = tid;                      // B chunk 0..511
    const int row = c >> 2;                 // 0..127
    const int cb = (c & 3) * 16;
    srcB = (long)row * 4096 + (cb ^ swz64(row));
    dstB = c * 16;
  }
  const int swzR = (lk * 16) ^ swz64(lr);

  f32x4 acc[4][4] = {};

  #define STGKV(s, reg)                                                    \
    {                                                                      \
      char* R_ = lds + (reg) * 24576;                                      \
      const long colB_ = (long)(s) * 64;                                   \
      _Pragma("unroll")                                                    \
      for (int j = 0; j < 2; ++j)                                          \
        gload16(Ab + srcA[j] + colB_, R_ + dstA[j]);                       \
      gload16(Bb + srcB + colB_, R_ + 16384 + dstB);                       \
    }

  const int S = 64;                          // K=2048 / 32
  STGKV(0, 0); STGKV(1, 1); STGKV(2, 2);
  int cur = 0;
  for (int s = 0; s < S; ++s) {
    if (s + 2 < S) { VMCNT(6); } else if (s + 1 < S) { VMCNT(3); } else { VMCNT(0); }
    SBAR(); SCHED0();
    {
      const char* R_ = lds + cur * 24576;
      bf16x8 af[4], bf[4];
      #pragma unroll
      for (int m = 0; m < 4; ++m)
        af[m] = *(const bf16x8*)(R_ + (wr * 64 + m * 16 + lr) * 64 + swzR);
      #pragma unroll
      for (int n = 0; n < 4; ++n)
        bf[n] = *(const bf16x8*)(R_ + 16384 + (wc * 64 + n * 16 + lr) * 64 + swzR);
      __builtin_amdgcn_s_setprio(1);
      #pragma unroll
      for (int m = 0; m < 4; ++m)
        #pragma unroll
        for (int n = 0; n < 4; ++n)
          acc[m][n] = __builtin_amdgcn_mfma_f32_16x16x32_bf16(af[m], bf[n], acc[m][n], 0, 0, 0);
      __builtin_amdgcn_s_setprio(0);
    }
    SBAR(); SCHED0();
    if (s + 3 < S) STGKV(s + 3, cur);
    cur = (cur == 2) ? 0 : cur + 1;
  }
  #undef STGKV

  const float* bias = (z == 0) ? bk : bv;
  u16* C = (z == 0) ? Kout : Vout;           // transposed (B,H,HD,S)
  #pragma unroll
  for (int m = 0; m < 4; ++m) {
    #pragma unroll
    for (int n = 0; n < 4; ++n) {
      const int gm0 = blockIdx.x * 256 + wr * 64 + m * 16 + lk * 4;
      const int gn  = blockIdx.y * 128 + wc * 64 + n * 16 + lr;
      float v4[4];
      #pragma unroll
      for (int i = 0; i < 4; ++i) {
        float val = acc[m][n][i] + bias[gn];
        if (z == 0)  // k: elu(x)+1
          val = (val > 0.f) ? (val + 1.f) : __builtin_exp2f(val * 1.4426950408889634f);
        v4[i] = val;
      }
      const int b = gm0 >> 11, s = gm0 & 2047;
      const int h = gn >> 7,  d = gn & 127;
      u16x4 p;
      p[0] = f2b(v4[0]); p[1] = f2b(v4[1]); p[2] = f2b(v4[2]); p[3] = f2b(v4[3]);
      *(u16x4*)(C + (long)((b * 16 + h) * 128 + d) * 2048 + s) = p;
    }
  }
}

// ---------------------------------------------------------------------------
// 128x128-tile z-batched bt-GEMM: ring + reg-dbuf + swz64 (tail kernels).
// Requires K % 64 == 0, K >= 128.
// ---------------------------------------------------------------------------
template<int ACT, int OUTMODE, int RESID, int ACCUM, int DIVDEN>
__global__ __launch_bounds__(256) void btgemm_kernel(
    const u16* __restrict__ A, const u16* __restrict__ Bt, void* Cv,
    const float* __restrict__ bias, const float* resid, const float* __restrict__ den,
    int M, int N, int K, int lda, int ldb, int ldc, int ZMOD,
    long sAh, long sAl, long sBh, long sBl, long sCh, long sCl, long sDh, long sDl)
{
  __shared__ char lds[65536];
  const int tid = threadIdx.x;
  const int wave = tid >> 6, lane = tid & 63;
  const int lr = lane & 15, lk = lane >> 4;
  const int wr = wave >> 1, wc = wave & 1;
  const int z = blockIdx.z;
  const int zh = z / ZMOD, zl = z % ZMOD;
  const char* Ab = (const char*)(A + zh * sAh + zl * sAl + (long)blockIdx.x * 128 * lda);
  const char* Bb = (const char*)(Bt + zh * sBh + zl * sBl + (long)blockIdx.y * 128 * ldb);
  const long ldaB = (long)lda * 2, ldbB = (long)ldb * 2;

  long srcA[2], srcB[2];
  int  dstO[2];
  #pragma unroll
  for (int j = 0; j < 2; ++j) {
    const int c = j * 256 + tid;            // chunk 0..511
    const int row = c >> 2;                 // 0..127 (64B rows)
    const int cb = (c & 3) * 16;
    srcA[j] = (long)row * ldaB + (cb ^ swz64(row));
    srcB[j] = (long)row * ldbB + (cb ^ swz64(row));
    dstO[j] = c * 16;
  }
  const int swzR = (lk * 16) ^ swz64(lr);

  f32x4 acc[4][4] = {};
  bf16x8 a_af[4], a_bf[4], b_af[4], b_bf[4];

  #define STG7(s)                                                          \
    { char* R_ = lds + ((s) & 3) * 16384; const long cB_ = (long)(s) * 64; \
      _Pragma("unroll") for (int j = 0; j < 2; ++j) {                      \
        gload16(Ab + srcA[j] + cB_, R_ + dstO[j]);                         \
        gload16(Bb + srcB[j] + cB_, R_ + 8192 + dstO[j]); } }

  #define RD7(P, s)                                                       \
    { const char* R_ = lds + ((s) & 3) * 16384;                            \
      _Pragma("unroll") for (int m = 0; m < 4; ++m)                        \
        P##af[m] = *(const bf16x8*)(R_ + (wr * 64 + m * 16 + lr) * 64 + swzR); \
      _Pragma("unroll") for (int n = 0; n < 4; ++n)                        \
        P##bf[n] = *(const bf16x8*)(R_ + 8192 + (wc * 64 + n * 16 + lr) * 64 + swzR); }

  #define MM7(P)                                                           \
    { __builtin_amdgcn_s_setprio(1);                                       \
      _Pragma("unroll") for (int m = 0; m < 4; ++m)                        \
        _Pragma("unroll") for (int n = 0; n < 4; ++n)                      \
          acc[m][n] = __builtin_amdgcn_mfma_f32_16x16x32_bf16(P##af[m], P##bf[n], acc[m][n], 0, 0, 0); \
      __builtin_amdgcn_s_setprio(0); }

  const int S = K >> 5;                     // even, >= 4
  STG7(0); STG7(1); STG7(2);
  VMCNT(8); SBAR(); SCHED0();
  RD7(a_, 0);
  for (int s = 0; s < S - 2; s += 2) {
    VMCNT(4); SBAR(); SCHED0();
    RD7(b_, s + 1);
    if (s + 3 < S) STG7(s + 3);
    SCHED0();
    MM7(a_);
    VMCNT(4); SBAR(); SCHED0();
    RD7(a_, s + 2);
    if (s + 4 < S) STG7(s + 4);
    SCHED0();
    MM7(b_);
  }
  VMCNT(0); SBAR(); SCHED0();
  RD7(b_, S - 1);
  SCHED0();
  MM7(a_);
  MM7(b_);
  #undef STG7
  #undef RD7
  #undef MM7

  const long cbase = (long)zh * sCh + (long)zl * sCl;
  #pragma unroll
  for (int m = 0; m < 4; ++m) {
    #pragma unroll
    for (int n = 0; n < 4; ++n) {
      const int gm0 = blockIdx.x * 128 + wr * 64 + m * 16 + lk * 4;
      const int gn  = blockIdx.y * 128 + wc * 64 + n * 16 + lr;
      float v4[4];
      #pragma unroll
      for (int i = 0; i < 4; ++i) {
        float val = acc[m][n][i];
        if (bias) val += bias[gn];
        if (ACT == 1) val = (val > 0.f) ? (val + 1.f) : __builtin_exp2f(val * 1.4426950408889634f);
        if (ACT == 2) val = gelu_f(val);
        if (DIVDEN) val = val / (den[(long)zh * sDh + (long)zl * sDl + gm0 + i] + 1e-6f);
        if (RESID) val += resid[cbase + (long)(gm0 + i) * ldc + gn];
        if (ACCUM) val += ((const float*)Cv)[cbase + (long)(gm0 + i) * ldc + gn];
        v4[i] = val;
      }
      if (OUTMODE == 0) {
        u16* C = (u16*)Cv;
        #pragma unroll
        for (int i = 0; i < 4; ++i) C[cbase + (long)(gm0 + i) * ldc + gn] = f2b(v4[i]);
      } else if (OUTMODE == 1) {
        float* C = (float*)Cv;
        #pragma unroll
        for (int i = 0; i < 4; ++i) C[cbase + (long)(gm0 + i) * ldc + gn] = v4[i];
      } else {
        u16* C = (u16*)Cv;
        const int b = gm0 >> 11, s = gm0 & 2047;
        const int h = gn >> 7,  d = gn & 127;
        u16x4 p;
        p[0] = f2b(v4[0]); p[1] = f2b(v4[1]); p[2] = f2b(v4[2]); p[3] = f2b(v4[3]);
        *(u16x4*)(C + (long)((b * 16 + h) * 128 + d) * 2048 + s) = p;
      }
    }
  }
}

// ---------------------------------------------------------------------------
// Fused FFN middle v5: 64-row M-tile, hg split 8 (grid 128x8), bf16 partials.
// 512 thr, LDS 72KB, 2 blocks/CU.
// ---------------------------------------------------------------------------
__global__ __launch_bounds__(512, 4) void ffnmid_kernel(
    const u16* __restrict__ T1,   // [8192][256] bf16
    const u16* __restrict__ W2T,  // [8192][256] bf16 (rows = HID)
    const u16* __restrict__ W3T,  // [256][8192] bf16 (rows = rank)
    const float* __restrict__ b2, // [8192]
    u16* __restrict__ RP)         // [8][8192][256] bf16 partials
{
  __shared__ char Wb[2][32768];   // W2s [32][512B] swz(r&7)<<4 ; W3s [256][64B] swz(r&3)<<4
  __shared__ char Ps[8192];       // [64][128B] swz(m&7)<<4, cols 0..63B used
  const int tid = threadIdx.x;
  const int wave = tid >> 6, lane = tid & 63;
  const int lr = lane & 15, lk = lane >> 4;
  const int wn  = wave & 1;       // stage-1 A(W2) n-frag (n0 = wn*16)
  const int wm  = wave >> 1;      // stage-1 B(T1) m-frag (m0 = wm*16)
  const int wmm = wave & 1;       // stage-2 m-group (m0 = wmm*32)
  const int wrr = wave >> 1;      // stage-2 r-group (r0 = wrr*64)
  const int mb = blockIdx.x, hg = blockIdx.y;

  // T1 fragment -> registers (B-operand layout: row=lr, k=lk*8+e), once.
  bf16x8 t1r[8];
  {
    const long row = (long)mb * 64 + wm * 16 + lr;
    #pragma unroll
    for (int kx = 0; kx < 8; ++kx)
      t1r[kx] = *(const bf16x8*)(T1 + row * 256 + kx * 32 + lk * 8);
  }

  #define STG_SLICE(it, buf)                                               \
    {                                                                      \
      const long h0_ = (long)hg * 1024 + (long)(it) * 32;                  \
      const char* s2_ = (const char*)W2T + h0_ * 512;                      \
      _Pragma("unroll")                                                    \
      for (int j = 0; j < 2; ++j) {                                        \
        const int c = j * 512 + tid;             /* 0..1023 */             \
        const int r = c >> 5;                    /* 0..31  */              \
        const int cb = (c & 31) * 16;                                      \
        gload16(s2_ + r * 512 + (cb ^ ((r & 7) << 4)), Wb[buf] + c * 16);  \
      }                                                                    \
      _Pragma("unroll")                                                    \
      for (int j = 0; j < 2; ++j) {                                        \
        const int c = j * 512 + tid;             /* 0..1023 */             \
        const int r = c >> 2;                    /* 0..255 */              \
        const int cb = (c & 3) * 16;                                       \
        gload16((const char*)W3T + (long)r * 16384 + h0_ * 2 +             \
                    (cb ^ ((r & 3) << 4)),                                 \
                Wb[buf] + 16384 + c * 16);                                 \
      }                                                                    \
    }

  const float* bbase = b2 + (long)hg * 1024 + wn * 16 + lk * 4;
  float4 bias = *(const float4*)bbase;
  STG_SLICE(0, 0);
  VMCNT(0); SBAR();

  f32x4 acc2[2][4] = {};

  for (int it = 0; it < 32; ++it) {
    const int cur = it & 1;
    const char* W2s = Wb[cur];
    const char* W3s = Wb[cur] + 16384;

    float4 bias_n = bias;
    if (it + 1 < 32) {
      STG_SLICE(it + 1, cur ^ 1);
      bias_n = *(const float4*)(bbase + (it + 1) * 32);
    }
    SCHED0();

    // stage-1: D(n,m) = W2slice @ T1^T   (32 x 64, K=256), T1 in regs
    f32x4 p = {};
    #pragma unroll
    for (int kx = 0; kx < 8; ++kx) {
      const int nn = wn * 16 + lr;           // A row
      bf16x8 w2f = *(const bf16x8*)(W2s + nn * 512 + (((kx * 32 + lk * 8) * 2) ^ ((nn & 7) << 4)));
      p = __builtin_amdgcn_mfma_f32_16x16x32_bf16(w2f, t1r[kx], p, 0, 0, 0);
    }
    // gelu + vector write: thread holds (n = wn*16+lk*4+i, m = wm*16+lr)
    {
      const int m = wm * 16 + lr;
      u16x4 pk;
      pk[0] = f2b(gelu_f(p[0] + bias.x));
      pk[1] = f2b(gelu_f(p[1] + bias.y));
      pk[2] = f2b(gelu_f(p[2] + bias.z));
      pk[3] = f2b(gelu_f(p[3] + bias.w));
      *(u16x4*)(Ps + m * 128 + ((wn * 32 + lk * 8) ^ ((m & 7) << 4))) = pk;
    }
    LGKMCNT0();   // cross-wave ds_write -> ds_read: drain before barrier
    SBAR();

    // stage-2: acc2 += P @ W3slice^T   (64 x 256, K=32), 2m x 4r frags
    {
      bf16x8 af[2], bf[4];
      #pragma unroll
      for (int fm = 0; fm < 2; ++fm) {
        const int m = wmm * 32 + fm * 16 + lr;
        af[fm] = *(const bf16x8*)(Ps + m * 128 + ((lk * 16) ^ ((m & 7) << 4)));
      }
      #pragma unroll
      for (int fr = 0; fr < 4; ++fr) {
        const int r = wrr * 64 + fr * 16 + lr;
        bf[fr] = *(const bf16x8*)(W3s + r * 64 + ((lk * 16) ^ ((r & 3) << 4)));
      }
      __builtin_amdgcn_s_setprio(1);
      #pragma unroll
      for (int fm = 0; fm < 2; ++fm)
        #pragma unroll
        for (int fr = 0; fr < 4; ++fr)
          acc2[fm][fr] = __builtin_amdgcn_mfma_f32_16x16x32_bf16(af[fm], bf[fr], acc2[fm][fr], 0, 0, 0);
      __builtin_amdgcn_s_setprio(0);
    }
    bias = bias_n;
    VMCNT(0);   // next slice + bias landed (overlapped with compute above)
    SBAR();     // Ps/W3s reads consumed -> safe to overwrite next iter
  }
  #undef STG_SLICE

  // epilogue: partial bf16 [64][256]
  u16* out = RP + (long)hg * 2097152 + (long)mb * 64 * 256;
  #pragma unroll
  for (int fm = 0; fm < 2; ++fm) {
    #pragma unroll
    for (int fr = 0; fr < 4; ++fr) {
      const int r = wrr * 64 + fr * 16 + lr;
      #pragma unroll
      for (int i = 0; i < 4; ++i) {
        const int m = wmm * 32 + fm * 16 + lk * 4 + i;
        out[(long)m * 256 + r] = f2b(acc2[fm][fr][i]);
      }
    }
  }
}

// ---------------------------------------------------------------------------
extern "C" void kernel_launch(void* const* d_in, const int* in_sizes, int n_in,
                              void* d_out, int out_size, void* d_ws, size_t ws_size,
                              hipStream_t stream) {
  const float* x   = (const float*)d_in[0];
  const float* Wq  = (const float*)d_in[1];
  const float* bq  = (const float*)d_in[2];
  const float* Wk  = (const float*)d_in[3];
  const float* bk  = (const float*)d_in[4];
  const float* Wv  = (const float*)d_in[5];
  const float* bv  = (const float*)d_in[6];
  const float* Wo  = (const float*)d_in[7];
  const float* bo  = (const float*)d_in[8];
  const float* g1  = (const float*)d_in[9];
  const float* be1 = (const float*)d_in[10];
  const float* g2  = (const float*)d_in[11];
  const float* be2 = (const float*)d_in[12];
  const float* W1  = (const float*)d_in[13];
  const float* b1  = (const float*)d_in[14];
  const float* W2  = (const float*)d_in[15];
  const float* b2  = (const float*)d_in[16];
  const float* W3  = (const float*)d_in[17];
  const float* b3  = (const float*)d_in[18];
  const float* W4  = (const float*)d_in[19];
  const float* b4  = (const float*)d_in[20];
  float* xout = (float*)d_out;
  char* ws = (char*)d_ws;

  // workspace layout (bytes); total ~172.6 MB
  constexpr long DD2 = 2048L * 2048 * 2;          // 8 MB
  constexpr size_t oWqT = 0;
  constexpr size_t oWkT = oWqT + DD2;
  constexpr size_t oWvT = oWkT + DD2;
  constexpr size_t oWoT = oWvT + DD2;
  constexpr size_t oW1T = oWoT + DD2;             // 256x2048 bf16 (1 MB)
  constexpr size_t oW2T = oW1T + 256L * 2048 * 2; // 8192x256 bf16 (4 MB)
  constexpr size_t oW3T = oW2T + 8192L * 256 * 2; // 256x8192 bf16 (4 MB)
  constexpr size_t oW4T = oW3T + 256L * 8192 * 2; // 2048x256 bf16 (1 MB)
  constexpr size_t oH1  = oW4T + 2048L * 256 * 2; // 32MB: h1 / kvpart / attnN / t1-partials
  constexpr size_t oQ   = oH1 + 8192L * 2048 * 2; // 32MB: q / h2 / t3b
  constexpr size_t oKT  = oQ  + 8192L * 2048 * 2; // 32MB: kT / t1
  constexpr size_t oVT  = oKT + 8192L * 2048 * 2; // 32MB: vT / ffn partials (bf16 x8)
  constexpr size_t oKVT = oVT + 8192L * 2048 * 2; // 64x128x128 bf16 (2MB)
  constexpr size_t oKS  = oKVT + 64L * 128 * 128 * 2;
  constexpr size_t oDEN = oKS + 64L * 128 * 4;

  u16* WqT = (u16*)(ws + oWqT);
  u16* WkT = (u16*)(ws + oWkT);
  u16* WvT = (u16*)(ws + oWvT);
  u16* WoT = (u16*)(ws + oWoT);
  u16* W1T = (u16*)(ws + oW1T);
  u16* W2T = (u16*)(ws + oW2T);
  u16* W3T = (u16*)(ws + oW3T);
  u16* W4T = (u16*)(ws + oW4T);
  u16* H1    = (u16*)(ws + oH1);    // h1; kv partials; attnN; t1 split-K partials
  float* KVP = (float*)(ws + oH1);
  float* RP1 = (float*)(ws + oH1);  // t1 partials [4][8192][256] f32
  u16* Qb    = (u16*)(ws + oQ);     // q; h2
  u16* T3B   = (u16*)(ws + oQ + 8L * 1024 * 1024); // t3 bf16 (4MB; h2 dead)
  u16* KT    = (u16*)(ws + oKT);    // kT; then t1
  u16* T1    = (u16*)(ws + oKT);
  u16* VT    = (u16*)(ws + oVT);    // vT; then ffn partials
  u16* RPF   = (u16*)(ws + oVT);    // ffn partials [8][8192][256] bf16 (32MB)
  u16* KVT = (u16*)(ws + oKVT);
  float* KS  = (float*)(ws + oKS);
  float* DEN = (float*)(ws + oDEN);
  u16* H2  = Qb;

  const dim3 tb32(32, 8);
  tpose_f32_bf16_kernel<<<dim3(64, 64), tb32, 0, stream>>>(Wq, WqT, 2048, 2048);
  tpose_f32_bf16_kernel<<<dim3(64, 64), tb32, 0, stream>>>(Wk, WkT, 2048, 2048);
  tpose_f32_bf16_kernel<<<dim3(64, 64), tb32, 0, stream>>>(Wv, WvT, 2048, 2048);
  tpose_f32_bf16_kernel<<<dim3(64, 64), tb32, 0, stream>>>(Wo, WoT, 2048, 2048);
  tpose_f32_bf16_kernel<<<dim3(8, 64),  tb32, 0, stream>>>(W1, W1T, 2048, 256);
  tpose_f32_bf16_kernel<<<dim3(256, 8), tb32, 0, stream>>>(W2, W2T, 256, 8192);
  tpose_f32_bf16_kernel<<<dim3(8, 256), tb32, 0, stream>>>(W3, W3T, 8192, 256);
  tpose_f32_bf16_kernel<<<dim3(64, 8),  tb32, 0, stream>>>(W4, W4T, 256, 2048);

  // h1 = LN1(x)
  ln_bf16_kernel<<<8192, 256, 0, stream>>>(x, g1, be1, H1);

  // q projection (swapped chain, vector stores) + k/v projections (unswapped)
  qkvQ_kernel<<<dim3(32, 16), 512, 0, stream>>>(H1, WqT, Qb, bq);
  qkvKV_kernel<<<dim3(32, 16, 2), 512, 0, stream>>>(H1, WqT, KT, VT, bk, bv);

  // ksum over S, den = q.ksum
  ksum_kernel<<<2048, 256, 0, stream>>>(KT, KS);
  den_kernel<<<8192, 256, 0, stream>>>(Qb, KS, DEN);

  // kv split-K (z = head*8 + K-chunk of 256) -> f32 partials -> reduce
  btgemm_kernel<0, 1, 0, 0, 0><<<dim3(1, 1, 512), 256, 0, stream>>>(
      VT, KT, KVP, nullptr, nullptr, nullptr, 128, 128, 256, 2048, 2048, 128, 8,
      262144, 256, 262144, 256, 16384, 1048576, 0, 0);
  kvreduce_kernel<<<1024, 256, 0, stream>>>(KVP, KVT);

  // num = q @ kvT ; /(den+eps) -> attnN (bf16, (B,S,D), into H1 region)
  btgemm_kernel<0, 0, 0, 0, 1><<<dim3(16, 1, 64), 256, 0, stream>>>(
      Qb, KVT, H1, nullptr, nullptr, DEN, 2048, 128, 128, 2048, 128, 2048, 16,
      4194304, 128, 262144, 16384, 4194304, 128, 32768, 2048);

  // x2 = x + attnN@Wo + bo -> d_out (f32)  [swapped-epilogue btg128]
  btg128_kernel<1, 1><<<dim3(32, 16), 512, 0, stream>>>(
      H1, WoT, xout, bo, x, 2048, 2048, 2048, 2048);

  // h2 = LN2(x2)
  ln_bf16_kernel<<<8192, 256, 0, stream>>>(xout, g2, be2, H2);

  // t1 = h2@W1 + b1 : split-K x4 (K-sub 512) -> reduce bf16
  btgemm_kernel<0, 1, 0, 0, 0><<<dim3(64, 2, 4), 256, 0, stream>>>(
      H2, W1T, RP1, nullptr, nullptr, nullptr, 8192, 256, 512, 2048, 2048, 256, 4,
      0, 512, 0, 512, 0, 2097152, 0, 0);
  rankreduce_kernel<4, 0, 0><<<2048, 256, 0, stream>>>(RP1, b1, T1);

  // fused FFN middle: t3 partials = gelu(t1@W2+b2)@W3, t2 never to HBM
  ffnmid_kernel<<<dim3(128, 8), 512, 0, stream>>>(T1, W2T, W3T, b2, RPF);
  rankreduce8b_kernel<<<2048, 256, 0, stream>>>(RPF, b3, T3B);

  // out = x2 + t3@W4 + b4 (resid = d_out)  [swapped-epilogue btg128, K=256]
  btg128_kernel<1, 1><<<dim3(32, 16), 512, 0, stream>>>(
      T3B, W4T, xout, b4, xout, 256, 256, 256, 2048);
}

// Round 20
// 658.341 us; speedup vs baseline: 4.9300x; 1.0075x over previous
//
#include <hip/hip_runtime.h>
#include <hip/hip_bf16.h>
#include <cstdint>

typedef float     f32x4  __attribute__((ext_vector_type(4)));
typedef __bf16    bf16x8 __attribute__((ext_vector_type(8)));
typedef unsigned short u16x4 __attribute__((ext_vector_type(4)));
typedef unsigned short u16x8 __attribute__((ext_vector_type(8)));
typedef unsigned short u16;

#define DI __device__ __forceinline__

DI float b2f(u16 u) { union { unsigned int i; float f; } x; x.i = ((unsigned int)u) << 16; return x.f; }
DI u16 f2b(float f) {
  union { float f; unsigned int i; } x; x.f = f;
  return (u16)((x.i + 0x7FFFu + ((x.i >> 16) & 1u)) >> 16);   // RNE
}

// direct global->LDS async copy, 16B per lane
DI void gload16(const void* g, void* l) {
  __builtin_amdgcn_global_load_lds(
      (const __attribute__((address_space(1))) unsigned int*)g,
      (__attribute__((address_space(3))) unsigned int*)l, 16, 0, 0);
}

#define VMCNT(n)  asm volatile("s_waitcnt vmcnt(" #n ")" ::: "memory")
#define LGKMCNT0() asm volatile("s_waitcnt lgkmcnt(0)" ::: "memory")
#define SBAR()    __builtin_amdgcn_s_barrier()
#define SCHED0()  __builtin_amdgcn_sched_barrier(0)

// 64B-row LDS swizzle: slot XOR (r ^ r>>2)&3
DI int swz64(int row) { return ((row ^ (row >> 2)) & 3) << 4; }

// gelu via identity 0.5u(1+tanh(y)) = u / (1 + exp2(-2.885390*y)); v_rcp_f32
// replaces the IEEE divide (~8 VALU ops saved; rcp err 1e-7 << bf16 rounding).
// Overflow-safe: u>>0 -> exp2(-big)=0 -> u; u<<0 -> exp2(+big)=inf -> rcp=0 -> 0.
DI float gelu_f(float u) {
  const float y = 0.7978845608028654f * (u + 0.044715f * u * u * u);
  const float e = __builtin_exp2f(y * -2.885390081777927f);
  return u * __builtin_amdgcn_rcpf(1.0f + e);
}

// ---------------------------------------------------------------------------
// Transpose + fp32->bf16 convert: src (R x C) f32 row-major -> dst (C x R) bf16
// ---------------------------------------------------------------------------
__global__ __launch_bounds__(256) void tpose_f32_bf16_kernel(
    const float* __restrict__ src, u16* __restrict__ dst, int R, int C)
{
  __shared__ float tile[32][33];
  const int c0 = blockIdx.x * 32, r0 = blockIdx.y * 32;
  const int tx = threadIdx.x, ty = threadIdx.y;
  #pragma unroll
  for (int i = 0; i < 4; ++i)
    tile[ty + i * 8][tx] = src[(long)(r0 + ty + i * 8) * C + c0 + tx];
  __syncthreads();
  #pragma unroll
  for (int i = 0; i < 4; ++i)
    dst[(long)(c0 + ty + i * 8) * R + r0 + tx] = f2b(tile[tx][ty + i * 8]);
}

// ---------------------------------------------------------------------------
// LayerNorm (row of 2048) fp32 -> bf16.
// ---------------------------------------------------------------------------
__global__ __launch_bounds__(256) void ln_bf16_kernel(
    const float* __restrict__ x, const float* __restrict__ gamma,
    const float* __restrict__ beta, u16* __restrict__ out)
{
  const long row = blockIdx.x;
  const float* xr = x + row * 2048;
  const int tid = threadIdx.x;
  float4 a = *(const float4*)(xr + tid * 8);
  float4 b = *(const float4*)(xr + tid * 8 + 4);
  float s  = a.x + a.y + a.z + a.w + b.x + b.y + b.z + b.w;
  float ss = a.x*a.x + a.y*a.y + a.z*a.z + a.w*a.w
           + b.x*b.x + b.y*b.y + b.z*b.z + b.w*b.w;
  #pragma unroll
  for (int off = 1; off < 64; off <<= 1) { s += __shfl_xor(s, off); ss += __shfl_xor(ss, off); }
  __shared__ float red[8];
  if ((tid & 63) == 0) { red[tid >> 6] = s; red[4 + (tid >> 6)] = ss; }
  __syncthreads();
  s  = red[0] + red[1] + red[2] + red[3];
  ss = red[4] + red[5] + red[6] + red[7];
  const float mu = s * (1.0f / 2048.0f);
  const float rs = rsqrtf(ss * (1.0f / 2048.0f) - mu * mu + 1e-5f);
  const float v[8] = {a.x, a.y, a.z, a.w, b.x, b.y, b.z, b.w};
  u16x8 o;
  #pragma unroll
  for (int j = 0; j < 8; ++j) {
    const int col = tid * 8 + j;
    o[j] = f2b((v[j] - mu) * rs * gamma[col] + beta[col]);
  }
  *(u16x8*)(out + row * 2048 + tid * 8) = o;
}

// ---------------------------------------------------------------------------
// ksum[d_row] = sum_s kT[d_row][s]
// ---------------------------------------------------------------------------
__global__ __launch_bounds__(256) void ksum_kernel(
    const u16* __restrict__ kT, float* __restrict__ ksum)
{
  const int gw = blockIdx.x * 4 + (threadIdx.x >> 6);
  const int lane = threadIdx.x & 63;
  const u16* r = kT + (long)gw * 2048;
  float s = 0.f;
  #pragma unroll
  for (int j = 0; j < 4; ++j) {
    u16x8 v = *(const u16x8*)(r + j * 512 + lane * 8);
    #pragma unroll
    for (int e = 0; e < 8; ++e) s += b2f(v[e]);
  }
  #pragma unroll
  for (int off = 1; off < 64; off <<= 1) s += __shfl_xor(s, off);
  if (lane == 0) ksum[gw] = s;
}

// ---------------------------------------------------------------------------
// den[b][h][s] = dot(q[b][s][h*128:], ksum[b][h][:])
// ---------------------------------------------------------------------------
__global__ __launch_bounds__(256) void den_kernel(
    const u16* __restrict__ q, const float* __restrict__ ksum, float* __restrict__ den)
{
  const long m = blockIdx.x;            // b*2048 + s
  const int tid = threadIdx.x;
  const int b = (int)(m >> 11);
  const int h = tid >> 4;
  const int dl = (tid & 15) * 8;
  const u16* qr = q + m * 2048 + h * 128 + dl;
  const float* ks = ksum + ((long)b * 16 + h) * 128 + dl;
  u16x8 v = *(const u16x8*)qr;
  float s = 0.f;
  #pragma unroll
  for (int e = 0; e < 8; ++e) s += b2f(v[e]) * ks[e];
  #pragma unroll
  for (int off = 1; off < 16; off <<= 1) s += __shfl_xor(s, off);
  if ((tid & 15) == 0) den[((long)b * 16 + h) * 2048 + (m & 2047)] = s;
}

// ---------------------------------------------------------------------------
// kv split-K reduce: out_bf16[i] = sum_{p<8} partial[p][i]
// ---------------------------------------------------------------------------
__global__ __launch_bounds__(256) void kvreduce_kernel(
    const float* __restrict__ p, u16* __restrict__ out)
{
  long i = ((long)blockIdx.x * 256 + threadIdx.x) * 4;
  float4 s = *(const float4*)(p + i);
  #pragma unroll
  for (int j = 1; j < 8; ++j) {
    float4 v = *(const float4*)(p + (long)j * 1048576 + i);
    s.x += v.x; s.y += v.y; s.z += v.z; s.w += v.w;
  }
  u16x4 o; o[0] = f2b(s.x); o[1] = f2b(s.y); o[2] = f2b(s.z); o[3] = f2b(s.w);
  *(u16x4*)(out + i) = o;
}

// ---------------------------------------------------------------------------
// RANK split-K reduce (f32 partials): out = sum_{p<NP} P[p] (+bias) (+old)
// ---------------------------------------------------------------------------
template<int NP, int OUTF32, int ACC>
__global__ __launch_bounds__(256) void rankreduce_kernel(
    const float* __restrict__ p, const float* __restrict__ bias, void* out)
{
  long i = ((long)blockIdx.x * 256 + threadIdx.x) * 4;
  float4 s = *(const float4*)(p + i);
  #pragma unroll
  for (int j = 1; j < NP; ++j) {
    float4 v = *(const float4*)(p + (long)j * 2097152 + i);
    s.x += v.x; s.y += v.y; s.z += v.z; s.w += v.w;
  }
  if (bias) {
    const int col = (int)(i & 255);
    s.x += bias[col]; s.y += bias[col + 1]; s.z += bias[col + 2]; s.w += bias[col + 3];
  }
  if (ACC) {
    float4 o = *(const float4*)((const float*)out + i);
    s.x += o.x; s.y += o.y; s.z += o.z; s.w += o.w;
  }
  if (OUTF32) {
    *(float4*)((float*)out + i) = s;
  } else {
    u16x4 o; o[0] = f2b(s.x); o[1] = f2b(s.y); o[2] = f2b(s.z); o[3] = f2b(s.w);
    *(u16x4*)((u16*)out + i) = o;
  }
}

// ---------------------------------------------------------------------------
// RANK reduce, 8 bf16 partials -> bf16 out (+bias)
// ---------------------------------------------------------------------------
__global__ __launch_bounds__(256) void rankreduce8b_kernel(
    const u16* __restrict__ p, const float* __restrict__ bias, u16* __restrict__ out)
{
  long i = ((long)blockIdx.x * 256 + threadIdx.x) * 4;
  float4 s = {0.f, 0.f, 0.f, 0.f};
  #pragma unroll
  for (int j = 0; j < 8; ++j) {
    u16x4 v = *(const u16x4*)(p + (long)j * 2097152 + i);
    s.x += b2f(v[0]); s.y += b2f(v[1]); s.z += b2f(v[2]); s.w += b2f(v[3]);
  }
  const int col = (int)(i & 255);
  s.x += bias[col]; s.y += bias[col + 1]; s.z += bias[col + 2]; s.w += bias[col + 3];
  u16x4 o; o[0] = f2b(s.x); o[1] = f2b(s.y); o[2] = f2b(s.z); o[3] = f2b(s.w);
  *(u16x4*)(out + i) = o;
}

// ---------------------------------------------------------------------------
// 256x128-tile bt-GEMM (ring-3 + swz64 + SWAPPED MFMA, proven):
// mfma(bf, af, acc) -> D(row=n, col=m): thread holds 4 consecutive N at fixed
// M -> float4/u16x4 stores + float4 resid loads along the contiguous N axis.
// grid (M/256, N/128). K % 32 == 0. 8 waves = 4M x 2N, acc[4][4] = 64 VGPR.
// ---------------------------------------------------------------------------
template<int OUTMODE, int RESID>
__global__ __launch_bounds__(512, 4) void btg128_kernel(
    const u16* __restrict__ A, const u16* __restrict__ Bt, void* Cv,
    const float* __restrict__ bias, const float* resid,
    int K, int lda, int ldb, int ldc)
{
  __shared__ char lds[73728];                // 3 regions x (A 16KB + B 8KB)
  const int tid = threadIdx.x;
  const int wave = tid >> 6, lane = tid & 63;
  const int lr = lane & 15, lk = lane >> 4;
  const int wr = wave >> 1, wc = wave & 1;   // 4M x 2N
  const char* Ab = (const char*)(A + (long)blockIdx.x * 256 * lda);
  const char* Bb = (const char*)(Bt + (long)blockIdx.y * 128 * ldb);
  const long ldaB = (long)lda * 2, ldbB = (long)ldb * 2;

  long srcA[2], srcB;
  int  dstA[2], dstB;
  #pragma unroll
  for (int j = 0; j < 2; ++j) {
    const int c = j * 512 + tid;            // A chunk 0..1023
    const int row = c >> 2;                 // 0..255 (64B rows)
    const int cb = (c & 3) * 16;
    srcA[j] = (long)row * ldaB + (cb ^ swz64(row));
    dstA[j] = c * 16;
  }
  {
    const int c = tid;                      // B chunk 0..511
    const int row = c >> 2;                 // 0..127
    const int cb = (c & 3) * 16;
    srcB = (long)row * ldbB + (cb ^ swz64(row));
    dstB = c * 16;
  }
  const int swzR = (lk * 16) ^ swz64(lr);

  f32x4 acc[4][4] = {};

  #define STGG(s, reg)                                                     \
    {                                                                      \
      char* R_ = lds + (reg) * 24576;                                      \
      const long colB_ = (long)(s) * 64;                                   \
      _Pragma("unroll")                                                    \
      for (int j = 0; j < 2; ++j)                                          \
        gload16(Ab + srcA[j] + colB_, R_ + dstA[j]);                       \
      gload16(Bb + srcB + colB_, R_ + 16384 + dstB);                       \
    }

  const int S = K >> 5;
  STGG(0, 0);
  if (S > 1) STGG(1, 1);
  if (S > 2) STGG(2, 2);
  int cur = 0;
  for (int s = 0; s < S; ++s) {
    if (s + 2 < S) { VMCNT(6); } else if (s + 1 < S) { VMCNT(3); } else { VMCNT(0); }
    SBAR(); SCHED0();
    {
      const char* R_ = lds + cur * 24576;
      bf16x8 af[4], bf[4];
      #pragma unroll
      for (int m = 0; m < 4; ++m)
        af[m] = *(const bf16x8*)(R_ + (wr * 64 + m * 16 + lr) * 64 + swzR);
      #pragma unroll
      for (int n = 0; n < 4; ++n)
        bf[n] = *(const bf16x8*)(R_ + 16384 + (wc * 64 + n * 16 + lr) * 64 + swzR);
      __builtin_amdgcn_s_setprio(1);
      #pragma unroll
      for (int m = 0; m < 4; ++m)
        #pragma unroll
        for (int n = 0; n < 4; ++n)
          acc[m][n] = __builtin_amdgcn_mfma_f32_16x16x32_bf16(bf[n], af[m], acc[m][n], 0, 0, 0);
      __builtin_amdgcn_s_setprio(0);
    }
    SBAR(); SCHED0();                        // all waves done reading region cur
    if (s + 3 < S) STGG(s + 3, cur);         // (s+3)%3 == s%3 == cur
    cur = (cur == 2) ? 0 : cur + 1;
  }
  #undef STGG

  // epilogue (swapped layout): thread holds rows=n (4 consec), col=m
  #pragma unroll
  for (int m = 0; m < 4; ++m) {
    #pragma unroll
    for (int n = 0; n < 4; ++n) {
      const int gm  = blockIdx.x * 256 + wr * 64 + m * 16 + lr;
      const int gn0 = blockIdx.y * 128 + wc * 64 + n * 16 + lk * 4;
      float4 bi = {0.f, 0.f, 0.f, 0.f};
      if (bias) bi = *(const float4*)(bias + gn0);
      float4 v4;
      v4.x = acc[m][n][0] + bi.x; v4.y = acc[m][n][1] + bi.y;
      v4.z = acc[m][n][2] + bi.z; v4.w = acc[m][n][3] + bi.w;
      if (RESID) {
        float4 r = *(const float4*)(resid + (long)gm * ldc + gn0);
        v4.x += r.x; v4.y += r.y; v4.z += r.z; v4.w += r.w;
      }
      if (OUTMODE == 0) {
        u16x4 pk; pk[0] = f2b(v4.x); pk[1] = f2b(v4.y); pk[2] = f2b(v4.z); pk[3] = f2b(v4.w);
        *(u16x4*)((u16*)Cv + (long)gm * ldc + gn0) = pk;
      } else {
        *(float4*)((float*)Cv + (long)gm * ldc + gn0) = v4;
      }
    }
  }
}

// ---------------------------------------------------------------------------
// Q projection (ring-3 + swz64 + SWAPPED MFMA, separate kernel, no spill):
// vectorized u16x4 Q stores. grid (32,16).
// ---------------------------------------------------------------------------
__global__ __launch_bounds__(512, 4) void qkvQ_kernel(
    const u16* __restrict__ A, const u16* __restrict__ WqT,
    u16* __restrict__ Qout, const float* __restrict__ bq)
{
  __shared__ char lds[73728];                // 3 regions x (A 16KB + B 8KB)
  const int tid = threadIdx.x;
  const int wave = tid >> 6, lane = tid & 63;
  const int lr = lane & 15, lk = lane >> 4;
  const int wr = wave >> 1, wc = wave & 1;   // 4M x 2N
  const char* Ab = (const char*)(A + (long)blockIdx.x * 256 * 2048);
  const char* Bb = (const char*)(WqT + (long)blockIdx.y * 128 * 2048);

  long srcA[2], srcB;
  int  dstA[2], dstB;
  #pragma unroll
  for (int j = 0; j < 2; ++j) {
    const int c = j * 512 + tid;            // A chunk 0..1023
    const int row = c >> 2;                 // 0..255 (64B rows)
    const int cb = (c & 3) * 16;
    srcA[j] = (long)row * 4096 + (cb ^ swz64(row));
    dstA[j] = c * 16;
  }
  {
    const int c = tid;                      // B chunk 0..511
    const int row = c >> 2;                 // 0..127
    const int cb = (c & 3) * 16;
    srcB = (long)row * 4096 + (cb ^ swz64(row));
    dstB = c * 16;
  }
  const int swzR = (lk * 16) ^ swz64(lr);

  f32x4 acc[4][4] = {};

  #define STGQ1(s, reg)                                                    \
    {                                                                      \
      char* R_ = lds + (reg) * 24576;                                      \
      const long colB_ = (long)(s) * 64;                                   \
      _Pragma("unroll")                                                    \
      for (int j = 0; j < 2; ++j)                                          \
        gload16(Ab + srcA[j] + colB_, R_ + dstA[j]);                       \
      gload16(Bb + srcB + colB_, R_ + 16384 + dstB);                       \
    }

  const int S = 64;                          // K=2048 / 32
  STGQ1(0, 0); STGQ1(1, 1); STGQ1(2, 2);
  int cur = 0;
  for (int s = 0; s < S; ++s) {
    if (s + 2 < S) { VMCNT(6); } else if (s + 1 < S) { VMCNT(3); } else { VMCNT(0); }
    SBAR(); SCHED0();
    {
      const char* R_ = lds + cur * 24576;
      bf16x8 af[4], bf[4];
      #pragma unroll
      for (int m = 0; m < 4; ++m)
        af[m] = *(const bf16x8*)(R_ + (wr * 64 + m * 16 + lr) * 64 + swzR);
      #pragma unroll
      for (int n = 0; n < 4; ++n)
        bf[n] = *(const bf16x8*)(R_ + 16384 + (wc * 64 + n * 16 + lr) * 64 + swzR);
      __builtin_amdgcn_s_setprio(1);
      #pragma unroll
      for (int m = 0; m < 4; ++m)
        #pragma unroll
        for (int n = 0; n < 4; ++n)
          acc[m][n] = __builtin_amdgcn_mfma_f32_16x16x32_bf16(bf[n], af[m], acc[m][n], 0, 0, 0);
      __builtin_amdgcn_s_setprio(0);
    }
    SBAR(); SCHED0();
    if (s + 3 < S) STGQ1(s + 3, cur);
    cur = (cur == 2) ? 0 : cur + 1;
  }
  #undef STGQ1

  // swapped layout: rows = n (4 consec at lk*4), col = m (lr) -> u16x4 along N
  #pragma unroll
  for (int m = 0; m < 4; ++m) {
    #pragma unroll
    for (int n = 0; n < 4; ++n) {
      const int gm  = blockIdx.x * 256 + wr * 64 + m * 16 + lr;
      const int gn0 = blockIdx.y * 128 + wc * 64 + n * 16 + lk * 4;
      float4 bi = *(const float4*)(bq + gn0);
      u16x4 pk;
      #pragma unroll
      for (int i = 0; i < 4; ++i) {
        float val = acc[m][n][i] + ((const float*)&bi)[i];
        val = (val > 0.f) ? (val + 1.f) : __builtin_exp2f(val * 1.4426950408889634f);
        pk[i] = f2b(val);
      }
      *(u16x4*)(Qout + (long)gm * 2048 + gn0) = pk;
    }
  }
}

// ---------------------------------------------------------------------------
// K/V projections (ring-3 + swz64, unswapped chain, transposed stores):
// grid (32,16,2): z=0 -> K (elu+1), z=1 -> V.
// ---------------------------------------------------------------------------
__global__ __launch_bounds__(512, 4) void qkvKV_kernel(
    const u16* __restrict__ A, const u16* __restrict__ Wt0,
    u16* __restrict__ Kout, u16* __restrict__ Vout,
    const float* __restrict__ bk, const float* __restrict__ bv)
{
  __shared__ char lds[73728];                // 3 regions x (A 16KB + B 8KB)
  const int tid = threadIdx.x;
  const int wave = tid >> 6, lane = tid & 63;
  const int lr = lane & 15, lk = lane >> 4;
  const int wr = wave >> 1, wc = wave & 1;   // 4M x 2N
  const int z = blockIdx.z;                  // 0=K, 1=V
  const char* Ab = (const char*)(A + (long)blockIdx.x * 256 * 2048);
  const char* Bb = (const char*)(Wt0 + (long)(z + 1) * 4194304 + (long)blockIdx.y * 128 * 2048);

  long srcA[2], srcB;
  int  dstA[2], dstB;
  #pragma unroll
  for (int j = 0; j < 2; ++j) {
    const int c = j * 512 + tid;            // A chunk 0..1023
    const int row = c >> 2;                 // 0..255 (64B rows)
    const int cb = (c & 3) * 16;
    srcA[j] = (long)row * 4096 + (cb ^ swz64(row));
    dstA[j] = c * 16;
  }
  {
    const int c = tid;                      // B chunk 0..511
    const int row = c >> 2;                 // 0..127
    const int cb = (c & 3) * 16;
    srcB = (long)row * 4096 + (cb ^ swz64(row));
    dstB = c * 16;
  }
  const int swzR = (lk * 16) ^ swz64(lr);

  f32x4 acc[4][4] = {};

  #define STGKV(s, reg)                                                    \
    {                                                                      \
      char* R_ = lds + (reg) * 24576;                                      \
      const long colB_ = (long)(s) * 64;                                   \
      _Pragma("unroll")                                                    \
      for (int j = 0; j < 2; ++j)                                          \
        gload16(Ab + srcA[j] + colB_, R_ + dstA[j]);                       \
      gload16(Bb + srcB + colB_, R_ + 16384 + dstB);                       \
    }

  const int S = 64;                          // K=2048 / 32
  STGKV(0, 0); STGKV(1, 1); STGKV(2, 2);
  int cur = 0;
  for (int s = 0; s < S; ++s) {
    if (s + 2 < S) { VMCNT(6); } else if (s + 1 < S) { VMCNT(3); } else { VMCNT(0); }
    SBAR(); SCHED0();
    {
      const char* R_ = lds + cur * 24576;
      bf16x8 af[4], bf[4];
      #pragma unroll
      for (int m = 0; m < 4; ++m)
        af[m] = *(const bf16x8*)(R_ + (wr * 64 + m * 16 + lr) * 64 + swzR);
      #pragma unroll
      for (int n = 0; n < 4; ++n)
        bf[n] = *(const bf16x8*)(R_ + 16384 + (wc * 64 + n * 16 + lr) * 64 + swzR);
      __builtin_amdgcn_s_setprio(1);
      #pragma unroll
      for (int m = 0; m < 4; ++m)
        #pragma unroll
        for (int n = 0; n < 4; ++n)
          acc[m][n] = __builtin_amdgcn_mfma_f32_16x16x32_bf16(af[m], bf[n], acc[m][n], 0, 0, 0);
      __builtin_amdgcn_s_setprio(0);
    }
    SBAR(); SCHED0();
    if (s + 3 < S) STGKV(s + 3, cur);
    cur = (cur == 2) ? 0 : cur + 1;
  }
  #undef STGKV

  const float* bias = (z == 0) ? bk : bv;
  u16* C = (z == 0) ? Kout : Vout;           // transposed (B,H,HD,S)
  #pragma unroll
  for (int m = 0; m < 4; ++m) {
    #pragma unroll
    for (int n = 0; n < 4; ++n) {
      const int gm0 = blockIdx.x * 256 + wr * 64 + m * 16 + lk * 4;
      const int gn  = blockIdx.y * 128 + wc * 64 + n * 16 + lr;
      float v4[4];
      #pragma unroll
      for (int i = 0; i < 4; ++i) {
        float val = acc[m][n][i] + bias[gn];
        if (z == 0)  // k: elu(x)+1
          val = (val > 0.f) ? (val + 1.f) : __builtin_exp2f(val * 1.4426950408889634f);
        v4[i] = val;
      }
      const int b = gm0 >> 11, s = gm0 & 2047;
      const int h = gn >> 7,  d = gn & 127;
      u16x4 p;
      p[0] = f2b(v4[0]); p[1] = f2b(v4[1]); p[2] = f2b(v4[2]); p[3] = f2b(v4[3]);
      *(u16x4*)(C + (long)((b * 16 + h) * 128 + d) * 2048 + s) = p;
    }
  }
}

// ---------------------------------------------------------------------------
// 128x128-tile z-batched bt-GEMM: ring + reg-dbuf + swz64 (tail kernels).
// Requires K % 64 == 0, K >= 128.
// ---------------------------------------------------------------------------
template<int ACT, int OUTMODE, int RESID, int ACCUM, int DIVDEN>
__global__ __launch_bounds__(256) void btgemm_kernel(
    const u16* __restrict__ A, const u16* __restrict__ Bt, void* Cv,
    const float* __restrict__ bias, const float* resid, const float* __restrict__ den,
    int M, int N, int K, int lda, int ldb, int ldc, int ZMOD,
    long sAh, long sAl, long sBh, long sBl, long sCh, long sCl, long sDh, long sDl)
{
  __shared__ char lds[65536];
  const int tid = threadIdx.x;
  const int wave = tid >> 6, lane = tid & 63;
  const int lr = lane & 15, lk = lane >> 4;
  const int wr = wave >> 1, wc = wave & 1;
  const int z = blockIdx.z;
  const int zh = z / ZMOD, zl = z % ZMOD;
  const char* Ab = (const char*)(A + zh * sAh + zl * sAl + (long)blockIdx.x * 128 * lda);
  const char* Bb = (const char*)(Bt + zh * sBh + zl * sBl + (long)blockIdx.y * 128 * ldb);
  const long ldaB = (long)lda * 2, ldbB = (long)ldb * 2;

  long srcA[2], srcB[2];
  int  dstO[2];
  #pragma unroll
  for (int j = 0; j < 2; ++j) {
    const int c = j * 256 + tid;            // chunk 0..511
    const int row = c >> 2;                 // 0..127 (64B rows)
    const int cb = (c & 3) * 16;
    srcA[j] = (long)row * ldaB + (cb ^ swz64(row));
    srcB[j] = (long)row * ldbB + (cb ^ swz64(row));
    dstO[j] = c * 16;
  }
  const int swzR = (lk * 16) ^ swz64(lr);

  f32x4 acc[4][4] = {};
  bf16x8 a_af[4], a_bf[4], b_af[4], b_bf[4];

  #define STG7(s)                                                          \
    { char* R_ = lds + ((s) & 3) * 16384; const long cB_ = (long)(s) * 64; \
      _Pragma("unroll") for (int j = 0; j < 2; ++j) {                      \
        gload16(Ab + srcA[j] + cB_, R_ + dstO[j]);                         \
        gload16(Bb + srcB[j] + cB_, R_ + 8192 + dstO[j]); } }

  #define RD7(P, s)                                                       \
    { const char* R_ = lds + ((s) & 3) * 16384;                            \
      _Pragma("unroll") for (int m = 0; m < 4; ++m)                        \
        P##af[m] = *(const bf16x8*)(R_ + (wr * 64 + m * 16 + lr) * 64 + swzR); \
      _Pragma("unroll") for (int n = 0; n < 4; ++n)                        \
        P##bf[n] = *(const bf16x8*)(R_ + 8192 + (wc * 64 + n * 16 + lr) * 64 + swzR); }

  #define MM7(P)                                                           \
    { __builtin_amdgcn_s_setprio(1);                                       \
      _Pragma("unroll") for (int m = 0; m < 4; ++m)                        \
        _Pragma("unroll") for (int n = 0; n < 4; ++n)                      \
          acc[m][n] = __builtin_amdgcn_mfma_f32_16x16x32_bf16(P##af[m], P##bf[n], acc[m][n], 0, 0, 0); \
      __builtin_amdgcn_s_setprio(0); }

  const int S = K >> 5;                     // even, >= 4
  STG7(0); STG7(1); STG7(2);
  VMCNT(8); SBAR(); SCHED0();
  RD7(a_, 0);
  for (int s = 0; s < S - 2; s += 2) {
    VMCNT(4); SBAR(); SCHED0();
    RD7(b_, s + 1);
    if (s + 3 < S) STG7(s + 3);
    SCHED0();
    MM7(a_);
    VMCNT(4); SBAR(); SCHED0();
    RD7(a_, s + 2);
    if (s + 4 < S) STG7(s + 4);
    SCHED0();
    MM7(b_);
  }
  VMCNT(0); SBAR(); SCHED0();
  RD7(b_, S - 1);
  SCHED0();
  MM7(a_);
  MM7(b_);
  #undef STG7
  #undef RD7
  #undef MM7

  const long cbase = (long)zh * sCh + (long)zl * sCl;
  #pragma unroll
  for (int m = 0; m < 4; ++m) {
    #pragma unroll
    for (int n = 0; n < 4; ++n) {
      const int gm0 = blockIdx.x * 128 + wr * 64 + m * 16 + lk * 4;
      const int gn  = blockIdx.y * 128 + wc * 64 + n * 16 + lr;
      float v4[4];
      #pragma unroll
      for (int i = 0; i < 4; ++i) {
        float val = acc[m][n][i];
        if (bias) val += bias[gn];
        if (ACT == 1) val = (val > 0.f) ? (val + 1.f) : __builtin_exp2f(val * 1.4426950408889634f);
        if (ACT == 2) val = gelu_f(val);
        if (DIVDEN) val = val * __builtin_amdgcn_rcpf(den[(long)zh * sDh + (long)zl * sDl + gm0 + i] + 1e-6f);
        if (RESID) val += resid[cbase + (long)(gm0 + i) * ldc + gn];
        if (ACCUM) val += ((const float*)Cv)[cbase + (long)(gm0 + i) * ldc + gn];
        v4[i] = val;
      }
      if (OUTMODE == 0) {
        u16* C = (u16*)Cv;
        #pragma unroll
        for (int i = 0; i < 4; ++i) C[cbase + (long)(gm0 + i) * ldc + gn] = f2b(v4[i]);
      } else if (OUTMODE == 1) {
        float* C = (float*)Cv;
        #pragma unroll
        for (int i = 0; i < 4; ++i) C[cbase + (long)(gm0 + i) * ldc + gn] = v4[i];
      } else {
        u16* C = (u16*)Cv;
        const int b = gm0 >> 11, s = gm0 & 2047;
        const int h = gn >> 7,  d = gn & 127;
        u16x4 p;
        p[0] = f2b(v4[0]); p[1] = f2b(v4[1]); p[2] = f2b(v4[2]); p[3] = f2b(v4[3]);
        *(u16x4*)(C + (long)((b * 16 + h) * 128 + d) * 2048 + s) = p;
      }
    }
  }
}

// ---------------------------------------------------------------------------
// Fused FFN middle v5: 64-row M-tile, hg split 8 (grid 128x8), bf16 partials.
// 512 thr, LDS 72KB, 2 blocks/CU.
// ---------------------------------------------------------------------------
__global__ __launch_bounds__(512, 4) void ffnmid_kernel(
    const u16* __restrict__ T1,   // [8192][256] bf16
    const u16* __restrict__ W2T,  // [8192][256] bf16 (rows = HID)
    const u16* __restrict__ W3T,  // [256][8192] bf16 (rows = rank)
    const float* __restrict__ b2, // [8192]
    u16* __restrict__ RP)         // [8][8192][256] bf16 partials
{
  __shared__ char Wb[2][32768];   // W2s [32][512B] swz(r&7)<<4 ; W3s [256][64B] swz(r&3)<<4
  __shared__ char Ps[8192];       // [64][128B] swz(m&7)<<4, cols 0..63B used
  const int tid = threadIdx.x;
  const int wave = tid >> 6, lane = tid & 63;
  const int lr = lane & 15, lk = lane >> 4;
  const int wn  = wave & 1;       // stage-1 A(W2) n-frag (n0 = wn*16)
  const int wm  = wave >> 1;      // stage-1 B(T1) m-frag (m0 = wm*16)
  const int wmm = wave & 1;       // stage-2 m-group (m0 = wmm*32)
  const int wrr = wave >> 1;      // stage-2 r-group (r0 = wrr*64)
  const int mb = blockIdx.x, hg = blockIdx.y;

  // T1 fragment -> registers (B-operand layout: row=lr, k=lk*8+e), once.
  bf16x8 t1r[8];
  {
    const long row = (long)mb * 64 + wm * 16 + lr;
    #pragma unroll
    for (int kx = 0; kx < 8; ++kx)
      t1r[kx] = *(const bf16x8*)(T1 + row * 256 + kx * 32 + lk * 8);
  }

  #define STG_SLICE(it, buf)                                               \
    {                                                                      \
      const long h0_ = (long)hg * 1024 + (long)(it) * 32;                  \
      const char* s2_ = (const char*)W2T + h0_ * 512;                      \
      _Pragma("unroll")                                                    \
      for (int j = 0; j < 2; ++j) {                                        \
        const int c = j * 512 + tid;             /* 0..1023 */             \
        const int r = c >> 5;                    /* 0..31  */              \
        const int cb = (c & 31) * 16;                                      \
        gload16(s2_ + r * 512 + (cb ^ ((r & 7) << 4)), Wb[buf] + c * 16);  \
      }                                                                    \
      _Pragma("unroll")                                                    \
      for (int j = 0; j < 2; ++j) {                                        \
        const int c = j * 512 + tid;             /* 0..1023 */             \
        const int r = c >> 2;                    /* 0..255 */              \
        const int cb = (c & 3) * 16;                                       \
        gload16((const char*)W3T + (long)r * 16384 + h0_ * 2 +             \
                    (cb ^ ((r & 3) << 4)),                                 \
                Wb[buf] + 16384 + c * 16);                                 \
      }                                                                    \
    }

  const float* bbase = b2 + (long)hg * 1024 + wn * 16 + lk * 4;
  float4 bias = *(const float4*)bbase;
  STG_SLICE(0, 0);
  VMCNT(0); SBAR();

  f32x4 acc2[2][4] = {};

  for (int it = 0; it < 32; ++it) {
    const int cur = it & 1;
    const char* W2s = Wb[cur];
    const char* W3s = Wb[cur] + 16384;

    float4 bias_n = bias;
    if (it + 1 < 32) {
      STG_SLICE(it + 1, cur ^ 1);
      bias_n = *(const float4*)(bbase + (it + 1) * 32);
    }
    SCHED0();

    // stage-1: D(n,m) = W2slice @ T1^T   (32 x 64, K=256), T1 in regs
    f32x4 p = {};
    #pragma unroll
    for (int kx = 0; kx < 8; ++kx) {
      const int nn = wn * 16 + lr;           // A row
      bf16x8 w2f = *(const bf16x8*)(W2s + nn * 512 + (((kx * 32 + lk * 8) * 2) ^ ((nn & 7) << 4)));
      p = __builtin_amdgcn_mfma_f32_16x16x32_bf16(w2f, t1r[kx], p, 0, 0, 0);
    }
    // gelu + vector write: thread holds (n = wn*16+lk*4+i, m = wm*16+lr)
    {
      const int m = wm * 16 + lr;
      u16x4 pk;
      pk[0] = f2b(gelu_f(p[0] + bias.x));
      pk[1] = f2b(gelu_f(p[1] + bias.y));
      pk[2] = f2b(gelu_f(p[2] + bias.z));
      pk[3] = f2b(gelu_f(p[3] + bias.w));
      *(u16x4*)(Ps + m * 128 + ((wn * 32 + lk * 8) ^ ((m & 7) << 4))) = pk;
    }
    LGKMCNT0();   // cross-wave ds_write -> ds_read: drain before barrier
    SBAR();

    // stage-2: acc2 += P @ W3slice^T   (64 x 256, K=32), 2m x 4r frags
    {
      bf16x8 af[2], bf[4];
      #pragma unroll
      for (int fm = 0; fm < 2; ++fm) {
        const int m = wmm * 32 + fm * 16 + lr;
        af[fm] = *(const bf16x8*)(Ps + m * 128 + ((lk * 16) ^ ((m & 7) << 4)));
      }
      #pragma unroll
      for (int fr = 0; fr < 4; ++fr) {
        const int r = wrr * 64 + fr * 16 + lr;
        bf[fr] = *(const bf16x8*)(W3s + r * 64 + ((lk * 16) ^ ((r & 3) << 4)));
      }
      __builtin_amdgcn_s_setprio(1);
      #pragma unroll
      for (int fm = 0; fm < 2; ++fm)
        #pragma unroll
        for (int fr = 0; fr < 4; ++fr)
          acc2[fm][fr] = __builtin_amdgcn_mfma_f32_16x16x32_bf16(af[fm], bf[fr], acc2[fm][fr], 0, 0, 0);
      __builtin_amdgcn_s_setprio(0);
    }
    bias = bias_n;
    VMCNT(0);   // next slice + bias landed (overlapped with compute above)
    SBAR();     // Ps/W3s reads consumed -> safe to overwrite next iter
  }
  #undef STG_SLICE

  // epilogue: partial bf16 [64][256]
  u16* out = RP + (long)hg * 2097152 + (long)mb * 64 * 256;
  #pragma unroll
  for (int fm = 0; fm < 2; ++fm) {
    #pragma unroll
    for (int fr = 0; fr < 4; ++fr) {
      const int r = wrr * 64 + fr * 16 + lr;
      #pragma unroll
      for (int i = 0; i < 4; ++i) {
        const int m = wmm * 32 + fm * 16 + lk * 4 + i;
        out[(long)m * 256 + r] = f2b(acc2[fm][fr][i]);
      }
    }
  }
}

// ---------------------------------------------------------------------------
extern "C" void kernel_launch(void* const* d_in, const int* in_sizes, int n_in,
                              void* d_out, int out_size, void* d_ws, size_t ws_size,
                              hipStream_t stream) {
  const float* x   = (const float*)d_in[0];
  const float* Wq  = (const float*)d_in[1];
  const float* bq  = (const float*)d_in[2];
  const float* Wk  = (const float*)d_in[3];
  const float* bk  = (const float*)d_in[4];
  const float* Wv  = (const float*)d_in[5];
  const float* bv  = (const float*)d_in[6];
  const float* Wo  = (const float*)d_in[7];
  const float* bo  = (const float*)d_in[8];
  const float* g1  = (const float*)d_in[9];
  const float* be1 = (const float*)d_in[10];
  const float* g2  = (const float*)d_in[11];
  const float* be2 = (const float*)d_in[12];
  const float* W1  = (const float*)d_in[13];
  const float* b1  = (const float*)d_in[14];
  const float* W2  = (const float*)d_in[15];
  const float* b2  = (const float*)d_in[16];
  const float* W3  = (const float*)d_in[17];
  const float* b3  = (const float*)d_in[18];
  const float* W4  = (const float*)d_in[19];
  const float* b4  = (const float*)d_in[20];
  float* xout = (float*)d_out;
  char* ws = (char*)d_ws;

  // workspace layout (bytes); total ~172.6 MB
  constexpr long DD2 = 2048L * 2048 * 2;          // 8 MB
  constexpr size_t oWqT = 0;
  constexpr size_t oWkT = oWqT + DD2;
  constexpr size_t oWvT = oWkT + DD2;
  constexpr size_t oWoT = oWvT + DD2;
  constexpr size_t oW1T = oWoT + DD2;             // 256x2048 bf16 (1 MB)
  constexpr size_t oW2T = oW1T + 256L * 2048 * 2; // 8192x256 bf16 (4 MB)
  constexpr size_t oW3T = oW2T + 8192L * 256 * 2; // 256x8192 bf16 (4 MB)
  constexpr size_t oW4T = oW3T + 256L * 8192 * 2; // 2048x256 bf16 (1 MB)
  constexpr size_t oH1  = oW4T + 2048L * 256 * 2; // 32MB: h1 / kvpart / attnN / t1-partials
  constexpr size_t oQ   = oH1 + 8192L * 2048 * 2; // 32MB: q / h2 / t3b
  constexpr size_t oKT  = oQ  + 8192L * 2048 * 2; // 32MB: kT / t1
  constexpr size_t oVT  = oKT + 8192L * 2048 * 2; // 32MB: vT / ffn partials (bf16 x8)
  constexpr size_t oKVT = oVT + 8192L * 2048 * 2; // 64x128x128 bf16 (2MB)
  constexpr size_t oKS  = oKVT + 64L * 128 * 128 * 2;
  constexpr size_t oDEN = oKS + 64L * 128 * 4;

  u16* WqT = (u16*)(ws + oWqT);
  u16* WkT = (u16*)(ws + oWkT);
  u16* WvT = (u16*)(ws + oWvT);
  u16* WoT = (u16*)(ws + oWoT);
  u16* W1T = (u16*)(ws + oW1T);
  u16* W2T = (u16*)(ws + oW2T);
  u16* W3T = (u16*)(ws + oW3T);
  u16* W4T = (u16*)(ws + oW4T);
  u16* H1    = (u16*)(ws + oH1);    // h1; kv partials; attnN; t1 split-K partials
  float* KVP = (float*)(ws + oH1);
  float* RP1 = (float*)(ws + oH1);  // t1 partials [4][8192][256] f32
  u16* Qb    = (u16*)(ws + oQ);     // q; h2
  u16* T3B   = (u16*)(ws + oQ + 8L * 1024 * 1024); // t3 bf16 (4MB; h2 dead)
  u16* KT    = (u16*)(ws + oKT);    // kT; then t1
  u16* T1    = (u16*)(ws + oKT);
  u16* VT    = (u16*)(ws + oVT);    // vT; then ffn partials
  u16* RPF   = (u16*)(ws + oVT);    // ffn partials [8][8192][256] bf16 (32MB)
  u16* KVT = (u16*)(ws + oKVT);
  float* KS  = (float*)(ws + oKS);
  float* DEN = (float*)(ws + oDEN);
  u16* H2  = Qb;

  const dim3 tb32(32, 8);
  tpose_f32_bf16_kernel<<<dim3(64, 64), tb32, 0, stream>>>(Wq, WqT, 2048, 2048);
  tpose_f32_bf16_kernel<<<dim3(64, 64), tb32, 0, stream>>>(Wk, WkT, 2048, 2048);
  tpose_f32_bf16_kernel<<<dim3(64, 64), tb32, 0, stream>>>(Wv, WvT, 2048, 2048);
  tpose_f32_bf16_kernel<<<dim3(64, 64), tb32, 0, stream>>>(Wo, WoT, 2048, 2048);
  tpose_f32_bf16_kernel<<<dim3(8, 64),  tb32, 0, stream>>>(W1, W1T, 2048, 256);
  tpose_f32_bf16_kernel<<<dim3(256, 8), tb32, 0, stream>>>(W2, W2T, 256, 8192);
  tpose_f32_bf16_kernel<<<dim3(8, 256), tb32, 0, stream>>>(W3, W3T, 8192, 256);
  tpose_f32_bf16_kernel<<<dim3(64, 8),  tb32, 0, stream>>>(W4, W4T, 256, 2048);

  // h1 = LN1(x)
  ln_bf16_kernel<<<8192, 256, 0, stream>>>(x, g1, be1, H1);

  // q projection (swapped chain, vector stores) + k/v projections (unswapped)
  qkvQ_kernel<<<dim3(32, 16), 512, 0, stream>>>(H1, WqT, Qb, bq);
  qkvKV_kernel<<<dim3(32, 16, 2), 512, 0, stream>>>(H1, WqT, KT, VT, bk, bv);

  // ksum over S, den = q.ksum
  ksum_kernel<<<2048, 256, 0, stream>>>(KT, KS);
  den_kernel<<<8192, 256, 0, stream>>>(Qb, KS, DEN);

  // kv split-K (z = head*8 + K-chunk of 256) -> f32 partials -> reduce
  btgemm_kernel<0, 1, 0, 0, 0><<<dim3(1, 1, 512), 256, 0, stream>>>(
      VT, KT, KVP, nullptr, nullptr, nullptr, 128, 128, 256, 2048, 2048, 128, 8,
      262144, 256, 262144, 256, 16384, 1048576, 0, 0);
  kvreduce_kernel<<<1024, 256, 0, stream>>>(KVP, KVT);

  // num = q @ kvT ; /(den+eps) -> attnN (bf16, (B,S,D), into H1 region)
  btgemm_kernel<0, 0, 0, 0, 1><<<dim3(16, 1, 64), 256, 0, stream>>>(
      Qb, KVT, H1, nullptr, nullptr, DEN, 2048, 128, 128, 2048, 128, 2048, 16,
      4194304, 128, 262144, 16384, 4194304, 128, 32768, 2048);

  // x2 = x + attnN@Wo + bo -> d_out (f32)  [swapped-epilogue btg128]
  btg128_kernel<1, 1><<<dim3(32, 16), 512, 0, stream>>>(
      H1, WoT, xout, bo, x, 2048, 2048, 2048, 2048);

  // h2 = LN2(x2)
  ln_bf16_kernel<<<8192, 256, 0, stream>>>(xout, g2, be2, H2);

  // t1 = h2@W1 + b1 : split-K x4 (K-sub 512) -> reduce bf16
  btgemm_kernel<0, 1, 0, 0, 0><<<dim3(64, 2, 4), 256, 0, stream>>>(
      H2, W1T, RP1, nullptr, nullptr, nullptr, 8192, 256, 512, 2048, 2048, 256, 4,
      0, 512, 0, 512, 0, 2097152, 0, 0);
  rankreduce_kernel<4, 0, 0><<<2048, 256, 0, stream>>>(RP1, b1, T1);

  // fused FFN middle: t3 partials = gelu(t1@W2+b2)@W3, t2 never to HBM
  ffnmid_kernel<<<dim3(128, 8), 512, 0, stream>>>(T1, W2T, W3T, b2, RPF);
  rankreduce8b_kernel<<<2048, 256, 0, stream>>>(RPF, b3, T3B);

  // out = x2 + t3@W4 + b4 (resid = d_out)  [swapped-epilogue btg128, K=256]
  btg128_kernel<1, 1><<<dim3(32, 16), 512, 0, stream>>>(
      T3B, W4T, xout, b4, xout, 256, 256, 256, 2048);
}